// Round 2
// baseline (626.997 us; speedup 1.0000x reference)
//
#include <hip/hip_runtime.h>

// Problem constants (B=8, A=3, H=200, W=304)
#define HWSZ 60800      // H*W
#define NA 3
#define NTOT 182400     // A*H*W
#define KSEL 2000
#define BUFCAP 2048
#define CANDCAP 8192
#define NBATCH 8
#define NSPLIT 32
#define LOG_MAX_F 4.135166556742356f   // log(1000/16) rounded to fp32

// ---- workspace layout (bytes) ----
#define OFF_BUF   0          // 8*2048*8 = 131072
#define OFF_H1    131072     // 8*2048*4 = 65536
#define OFF_H2    196608     // 8*2048*4 = 65536
#define OFF_CNT   262144     // 8*4 = 32
#define OFF_CCNT  262176     // 8*4 = 32
#define ZR_START  131072
#define ZR_BYTES  131136     // zeroes H1,H2,CNT,CCNT
#define OFF_SEL   262208     // 8*16 = 128
#define OFF_BOX   262336     // 8*2000*16 = 256000 (16B aligned)
#define OFF_VALID 518336     // 8*2000*4 = 64000
#define OFF_SUP   582336     // 8*2000*32*8 = 4096000
#define OFF_CAND  582336     // overlay on sup (disjoint lifetime): 8*8192*8 = 524288

__device__ __forceinline__ unsigned int xform(float f) {
    unsigned int b = __float_as_uint(f);
    return b ^ ((unsigned int)((int)b >> 31) | 0x80000000u);  // monotonic float->uint
}

// ---------------- Kernel A: per-batch 2048-bin hist of top-11 key bits ----------------
__global__ __launch_bounds__(256) void k_hist1(const float* __restrict__ cls,
                                               unsigned int* __restrict__ hist1) {
    int b = blockIdx.y, part = blockIdx.x, tid = threadIdx.x;
    __shared__ unsigned int h[2048];
    for (int i = tid; i < 2048; i += 256) h[i] = 0u;
    __syncthreads();
    const float* base = cls + (size_t)b * NTOT;
    int per = (NTOT + NSPLIT - 1) / NSPLIT;
    int lo = part * per, hi = lo + per;
    if (hi > NTOT) hi = NTOT;
    for (int i = lo + tid; i < hi; i += 256)
        atomicAdd(&h[xform(base[i]) >> 21], 1u);
    __syncthreads();
    unsigned int* gh = hist1 + b * 2048;
    for (int i = tid; i < 2048; i += 256)
        if (h[i]) atomicAdd(&gh[i], h[i]);
}

// ---------------- Kernel B: suffix-scan hist1, find threshold bin ----------------
__global__ __launch_bounds__(1024) void k_scan1(const unsigned int* __restrict__ hist1,
                                                uint4* __restrict__ selinfo) {
    int b = blockIdx.x, tid = threadIdx.x;
    __shared__ unsigned int sa[2048], sb[2048];
    const unsigned int* h = hist1 + b * 2048;
    sa[tid] = h[tid];
    sa[tid + 1024] = h[tid + 1024];
    unsigned int* src = sa; unsigned int* dst = sb;
    for (int d = 1; d < 2048; d <<= 1) {
        __syncthreads();
        dst[tid] = src[tid] + ((tid + d < 2048) ? src[tid + d] : 0u);
        int i2 = tid + 1024;
        dst[i2] = src[i2] + ((i2 + d < 2048) ? src[i2 + d] : 0u);
        unsigned int* t = src; src = dst; dst = t;
    }
    __syncthreads();
    #pragma unroll
    for (int k = 0; k < 2; ++k) {
        int i = tid + k * 1024;
        unsigned int c = src[i];
        unsigned int cn = (i < 2047) ? src[i + 1] : 0u;
        if (c >= KSEL && cn < KSEL)
            selinfo[b] = make_uint4((unsigned int)i, cn, KSEL - cn, 0u);
    }
}

// -------- Kernel C: emit definite keys, collect in-bin candidates + sub-hist --------
__global__ __launch_bounds__(256) void k_pass2(const float* __restrict__ cls,
                                               const uint4* __restrict__ selinfo,
                                               unsigned long long* __restrict__ buf,
                                               unsigned int* __restrict__ cnt,
                                               unsigned long long* __restrict__ cand,
                                               unsigned int* __restrict__ ccnt,
                                               unsigned int* __restrict__ hist2) {
    int b = blockIdx.y, part = blockIdx.x, tid = threadIdx.x;
    unsigned int bin = selinfo[b].x;
    const float* base = cls + (size_t)b * NTOT;
    int per = (NTOT + NSPLIT - 1) / NSPLIT;
    int lo = part * per, hi = lo + per;
    if (hi > NTOT) hi = NTOT;
    for (int idx = lo + tid; idx < hi; idx += 256) {
        unsigned int u = xform(base[idx]);
        unsigned int bu = u >> 21;
        if (bu < bin) continue;
        int a = idx / HWSZ;
        int hw = idx - a * HWSZ;
        unsigned int n = (unsigned int)(hw * NA + a);
        unsigned long long key = ((unsigned long long)u << 32) | (unsigned long long)(~n);
        if (bu > bin) {
            unsigned int pos = atomicAdd(&cnt[b], 1u);
            if (pos < BUFCAP) buf[(size_t)b * BUFCAP + pos] = key;
        } else {
            atomicAdd(&hist2[b * 2048 + ((u >> 10) & 2047u)], 1u);
            unsigned int pos = atomicAdd(&ccnt[b], 1u);
            if (pos < CANDCAP) cand[(size_t)b * CANDCAP + pos] = key;
        }
    }
}

// -------- Kernel D: scan hist2 -> final threshold, append qualifying candidates --------
__global__ __launch_bounds__(1024) void k_finalize(const unsigned int* __restrict__ hist2,
                                                   const uint4* __restrict__ selinfo,
                                                   const unsigned long long* __restrict__ cand,
                                                   const unsigned int* __restrict__ ccnt,
                                                   unsigned long long* __restrict__ buf,
                                                   unsigned int* __restrict__ cnt) {
    int b = blockIdx.x, tid = threadIdx.x;
    __shared__ unsigned int sa[2048], sb[2048];
    __shared__ unsigned int shT;
    uint4 si = selinfo[b];
    unsigned int bin = si.x, krem = si.z;
    const unsigned int* h = hist2 + b * 2048;
    sa[tid] = h[tid];
    sa[tid + 1024] = h[tid + 1024];
    unsigned int* src = sa; unsigned int* dst = sb;
    for (int d = 1; d < 2048; d <<= 1) {
        __syncthreads();
        dst[tid] = src[tid] + ((tid + d < 2048) ? src[tid + d] : 0u);
        int i2 = tid + 1024;
        dst[i2] = src[i2] + ((i2 + d < 2048) ? src[i2 + d] : 0u);
        unsigned int* t = src; src = dst; dst = t;
    }
    __syncthreads();
    #pragma unroll
    for (int k = 0; k < 2; ++k) {
        int i = tid + k * 1024;
        unsigned int c = src[i];
        unsigned int cn = (i < 2047) ? src[i + 1] : 0u;
        if (c >= krem && cn < krem)
            shT = (bin << 21) | ((unsigned int)i << 10);
    }
    __syncthreads();
    unsigned int T = shT;
    unsigned int m = ccnt[b];
    if (m > CANDCAP) m = CANDCAP;
    for (unsigned int i = tid; i < m; i += 1024) {
        unsigned long long key = cand[(size_t)b * CANDCAP + i];
        if ((unsigned int)(key >> 32) >= T) {
            unsigned int pos = atomicAdd(&cnt[b], 1u);
            if (pos < BUFCAP) buf[(size_t)b * BUFCAP + pos] = key;
        }
    }
}

// -------- Kernel 2: per-batch bitonic sort (desc) + box decode --------
__global__ __launch_bounds__(1024) void k_sort_decode(
        const unsigned long long* __restrict__ buf,
        const unsigned int* __restrict__ cnt_in,
        const float* __restrict__ regs,
        const float* __restrict__ anchors,
        const int* __restrict__ img_h,
        const int* __restrict__ img_w,
        float* __restrict__ out_scores,
        float4* __restrict__ boxes_ws,
        unsigned int* __restrict__ valid_ws) {
    int b = blockIdx.x;
    int tid = threadIdx.x;
    __shared__ unsigned long long arr[BUFCAP];
    unsigned int cnt = cnt_in[b];
    if (cnt > BUFCAP) cnt = BUFCAP;
    for (int i = tid; i < BUFCAP; i += 1024)
        arr[i] = (i < (int)cnt) ? buf[(size_t)b * BUFCAP + i] : 0ULL;
    __syncthreads();

    for (int k = 2; k <= BUFCAP; k <<= 1) {
        for (int j = k >> 1; j > 0; j >>= 1) {
            for (int i = tid; i < BUFCAP; i += 1024) {
                int ixj = i ^ j;
                if (ixj > i) {
                    unsigned long long x = arr[i], y = arr[ixj];
                    bool up = (i & k) == 0;
                    if (up ? (x < y) : (x > y)) { arr[i] = y; arr[ixj] = x; }
                }
            }
            __syncthreads();
        }
    }

    int hv = img_h[0];
    int wv = img_w[0];
    float himg = (hv > 0 && hv < 100000) ? (float)hv : __int_as_float(hv);
    float wimg = (wv > 0 && wv < 100000) ? (float)wv : __int_as_float(wv);

    for (int r = tid; r < KSEL; r += 1024) {
        unsigned long long packed = arr[r];
        size_t o = (size_t)b * KSEL + r;
        if (packed == 0ULL) {
            out_scores[o] = 0.f;
            boxes_ws[o] = make_float4(0.f, 0.f, 0.f, 0.f);
            valid_ws[o] = 0u;
            continue;
        }
        unsigned int u = (unsigned int)(packed >> 32);
        unsigned int n = ~((unsigned int)packed);
        unsigned int bits = (u & 0x80000000u) ? (u & 0x7FFFFFFFu) : ~u;
        float score = __uint_as_float(bits);
        int a = (int)(n % NA);
        int hw = (int)(n / NA);
        const float* rp = regs + ((size_t)b * (4 * NA) + 4 * a) * HWSZ + hw;
        float dx = rp[0 * HWSZ];
        float dy = rp[1 * HWSZ];
        float dh = rp[2 * HWSZ];
        float dw = rp[3 * HWSZ];
        const float* ap = anchors + ((size_t)b * NTOT + n) * 4;
        float ax1 = ap[0], ay1 = ap[1], ax2 = ap[2], ay2 = ap[3];
        float ahh = ay2 - ay1;
        float aww = ax2 - ax1;
        float cx = aww * 0.5f;
        float cy = ahh * 0.5f;
        float px = cx + dx * aww;
        float py = cy + dy * ahh;
        dh = fminf(dh, LOG_MAX_F);
        dw = fminf(dw, LOG_MAX_F);
        float ph = expf(dh) * ahh;
        float pw = expf(dw) * aww;
        float x1 = px - pw * 0.5f;
        float y1 = py - ph * 0.5f;
        float x2 = px + pw * 0.5f;
        float y2 = py + ph * 0.5f;
        float bwv = fminf(fmaxf(x2, 0.f), wimg) - fminf(fmaxf(x1, 0.f), wimg);
        float bhv = fminf(fmaxf(y2, 0.f), himg) - fminf(fmaxf(y1, 0.f), himg);
        unsigned int valid = (bwv >= 16.f && bhv >= 16.f) ? 1u : 0u;
        out_scores[o] = score;
        boxes_ws[o] = make_float4(x1, y1, x2, y2);
        valid_ws[o] = valid;
    }
}

// -------- Kernel 3: suppression bitmask matrix (rows x 64-col words) --------
__global__ __launch_bounds__(64) void k_supmat(const float4* __restrict__ boxes_ws,
                                               unsigned long long* __restrict__ sup) {
    int ct = blockIdx.x;
    int rt = blockIdx.y;
    int b  = blockIdx.z;
    int tid = threadIdx.x;
    __shared__ float4 colbox[64];
    int j0 = ct * 64;
    int jl = j0 + tid;
    colbox[tid] = (jl < KSEL) ? boxes_ws[(size_t)b * KSEL + jl]
                              : make_float4(0.f, 0.f, 0.f, 0.f);
    __syncthreads();
    int i = rt * 64 + tid;
    if (i >= KSEL) return;
    float4 bi = boxes_ws[(size_t)b * KSEL + i];
    float area_i = (bi.z - bi.x) * (bi.w - bi.y);
    unsigned long long word = 0ULL;
    #pragma unroll 8
    for (int jj = 0; jj < 64; ++jj) {
        int j = j0 + jj;
        float4 bj = colbox[jj];
        float area_j = (bj.z - bj.x) * (bj.w - bj.y);
        float ix1 = fmaxf(bi.x, bj.x);
        float iy1 = fmaxf(bi.y, bj.y);
        float ix2 = fminf(bi.z, bj.z);
        float iy2 = fminf(bi.w, bj.w);
        float iw = fmaxf(ix2 - ix1, 0.f);
        float ih = fmaxf(iy2 - iy1, 0.f);
        float inter = iw * ih;
        float uni = area_i + area_j - inter;
        float iou = inter / fmaxf(uni, 1e-6f);
        bool s = (j > i) && (j < KSEL) && (iou > 0.7f);
        if (s) word |= (1ULL << jj);
    }
    sup[((size_t)b * KSEL + i) * 32 + ct] = word;
}

// -------- Kernel 4: word-tile greedy scan (1 wave / batch) + outputs --------
__global__ __launch_bounds__(64) void k_nms_scan(const unsigned long long* __restrict__ sup,
                                                 const unsigned int* __restrict__ valid_ws,
                                                 const float4* __restrict__ boxes_ws,
                                                 float* __restrict__ out_boxes,
                                                 float* __restrict__ out_keep) {
    int b = blockIdx.x;
    int lane = threadIdx.x;
    unsigned long long kw = 0ULL;   // lane<32 holds keep-word `lane`
    if (lane < 32) {
        const uint4* vv = (const uint4*)(valid_ws + (size_t)b * KSEL);
        #pragma unroll 4
        for (int q = 0; q < 16; ++q) {
            uint4 x = vv[lane * 16 + q];
            int base = q * 4;
            if (x.x) kw |= 1ULL << (base + 0);
            if (x.y) kw |= 1ULL << (base + 1);
            if (x.z) kw |= 1ULL << (base + 2);
            if (x.w) kw |= 1ULL << (base + 3);
        }
        if (lane == 31) kw &= 0xFFFFULL;   // rows 2000..2047 invalid
    }
    const unsigned long long* srow = sup + (size_t)b * KSEL * 32;
    __shared__ unsigned long long tile[64];

    for (int w = 0; w < 32; ++w) {
        int r = w * 64 + lane;
        unsigned long long diag = (r < KSEL) ? srow[(size_t)r * 32 + w] : 0ULL;
        unsigned long long cur = __shfl(kw, w, 64);   // word w's current keep bits
        tile[lane] = diag;
        __syncthreads();
        // resolve the 64-step greedy chain within this word (all lanes redundantly)
        #pragma unroll 16
        for (int bit = 0; bit < 64; ++bit) {
            unsigned long long d = tile[bit];
            if ((cur >> bit) & 1ULL) cur &= ~d;
        }
        if (lane == w) kw = cur;
        // apply kept rows' suppression to all later words (wave-uniform branches)
        #pragma unroll 4
        for (int bit = 0; bit < 64; ++bit) {
            if ((cur >> bit) & 1ULL) {
                int i = w * 64 + bit;
                if (lane < 32) kw &= ~srow[(size_t)i * 32 + lane];
            }
        }
        __syncthreads();
    }

    __shared__ unsigned long long kws[32];
    if (lane < 32) kws[lane] = kw;
    __syncthreads();
    for (int r = lane; r < KSEL; r += 64) {
        float kf = (float)((kws[r >> 6] >> (r & 63)) & 1ULL);
        size_t o = (size_t)b * KSEL + r;
        out_keep[o] = kf;
        float4 bx = boxes_ws[o];
        float* ob = out_boxes + o * 4;
        ob[0] = bx.x * kf;
        ob[1] = bx.y * kf;
        ob[2] = bx.z * kf;
        ob[3] = bx.w * kf;
    }
}

extern "C" void kernel_launch(void* const* d_in, const int* in_sizes, int n_in,
                              void* d_out, int out_size, void* d_ws, size_t ws_size,
                              hipStream_t stream) {
    const float* cls     = (const float*)d_in[0];
    const float* regs    = (const float*)d_in[1];
    const float* anchors = (const float*)d_in[2];
    const int*   img_h   = (const int*)d_in[3];
    const int*   img_w   = (const int*)d_in[4];

    float* out = (float*)d_out;
    float* out_boxes  = out;            // 8*2000*4
    float* out_scores = out + 64000;    // 8*2000
    float* out_keep   = out + 80000;    // 8*2000

    char* ws = (char*)d_ws;
    unsigned long long* buf  = (unsigned long long*)(ws + OFF_BUF);
    unsigned int* hist1      = (unsigned int*)(ws + OFF_H1);
    unsigned int* hist2      = (unsigned int*)(ws + OFF_H2);
    unsigned int* cnt        = (unsigned int*)(ws + OFF_CNT);
    unsigned int* ccnt       = (unsigned int*)(ws + OFF_CCNT);
    uint4* selinfo           = (uint4*)(ws + OFF_SEL);
    float4* boxes_ws         = (float4*)(ws + OFF_BOX);
    unsigned int* valid_ws   = (unsigned int*)(ws + OFF_VALID);
    unsigned long long* sup  = (unsigned long long*)(ws + OFF_SUP);
    unsigned long long* cand = (unsigned long long*)(ws + OFF_CAND);

    hipMemsetAsync(ws + ZR_START, 0, ZR_BYTES, stream);
    k_hist1<<<dim3(NSPLIT, NBATCH), 256, 0, stream>>>(cls, hist1);
    k_scan1<<<NBATCH, 1024, 0, stream>>>(hist1, selinfo);
    k_pass2<<<dim3(NSPLIT, NBATCH), 256, 0, stream>>>(cls, selinfo, buf, cnt, cand, ccnt, hist2);
    k_finalize<<<NBATCH, 1024, 0, stream>>>(hist2, selinfo, cand, ccnt, buf, cnt);
    k_sort_decode<<<NBATCH, 1024, 0, stream>>>(buf, cnt, regs, anchors, img_h, img_w,
                                               out_scores, boxes_ws, valid_ws);
    k_supmat<<<dim3(32, 32, NBATCH), 64, 0, stream>>>(boxes_ws, sup);
    k_nms_scan<<<NBATCH, 64, 0, stream>>>(sup, valid_ws, boxes_ws, out_boxes, out_keep);
}

// Round 3
// 366.650 us; speedup vs baseline: 1.7101x; 1.7101x over previous
//
#include <hip/hip_runtime.h>

// Problem constants (B=8, A=3, H=200, W=304)
#define HWSZ 60800      // H*W
#define NA 3
#define NTOT 182400     // A*H*W
#define KSEL 2000
#define BUFCAP 2048
#define CANDCAP 8192
#define NBATCH 8
#define GSPLIT 128
#define LOG_MAX_F 4.135166556742356f   // log(1000/16) rounded to fp32

// ---- workspace layout (bytes) ----
#define OFF_H1    0          // 8*2048*4 = 65536
#define OFF_CCNT  65536      // 8*4 = 32
#define ZR_BYTES  65568      // zeroes H1 + CCNT
#define OFF_SEL   65568      // 8*16 = 128 (16B aligned)
#define OFF_BOX   65696      // 8*2000*16 = 256000 (16B aligned)
#define OFF_VALID 321696     // 8*2000*4 = 64000
#define OFF_SUP   385696     // 8*2000*32*8 = 4096000 (8B aligned)
#define OFF_CAND  385696     // overlay on sup (disjoint lifetime): 8*8192*8 = 524288

__device__ __forceinline__ unsigned int xform(float f) {
    unsigned int b = __float_as_uint(f);
    return b ^ ((unsigned int)((int)b >> 31) | 0x80000000u);  // monotonic float->uint
}

// ---------------- Kernel A: per-batch 2048-bin hist of top-11 key bits ----------------
__global__ __launch_bounds__(256) void k_hist1(const float* __restrict__ cls,
                                               unsigned int* __restrict__ hist1) {
    int b = blockIdx.y, part = blockIdx.x, tid = threadIdx.x;
    __shared__ unsigned int h[2048];
    for (int i = tid; i < 2048; i += 256) h[i] = 0u;
    __syncthreads();
    const float4* base4 = (const float4*)(cls + (size_t)b * NTOT);
    const int n4 = NTOT / 4;                    // 45600
    int per = (n4 + GSPLIT - 1) / GSPLIT;       // 357
    int lo = part * per, hi = lo + per;
    if (hi > n4) hi = n4;
    for (int i = lo + tid; i < hi; i += 256) {
        float4 v = base4[i];
        atomicAdd(&h[xform(v.x) >> 21], 1u);
        atomicAdd(&h[xform(v.y) >> 21], 1u);
        atomicAdd(&h[xform(v.z) >> 21], 1u);
        atomicAdd(&h[xform(v.w) >> 21], 1u);
    }
    __syncthreads();
    unsigned int* gh = hist1 + b * 2048;
    for (int i = tid; i < 2048; i += 256)
        if (h[i]) atomicAdd(&gh[i], h[i]);
}

// ---------------- Kernel B: suffix-scan hist1, find threshold bin ----------------
__global__ __launch_bounds__(1024) void k_scan1(const unsigned int* __restrict__ hist1,
                                                uint4* __restrict__ selinfo) {
    int b = blockIdx.x, tid = threadIdx.x;
    __shared__ unsigned int sa[2048], sb[2048];
    const unsigned int* h = hist1 + b * 2048;
    sa[tid] = h[tid];
    sa[tid + 1024] = h[tid + 1024];
    unsigned int* src = sa; unsigned int* dst = sb;
    for (int d = 1; d < 2048; d <<= 1) {
        __syncthreads();
        dst[tid] = src[tid] + ((tid + d < 2048) ? src[tid + d] : 0u);
        int i2 = tid + 1024;
        dst[i2] = src[i2] + ((i2 + d < 2048) ? src[i2 + d] : 0u);
        unsigned int* t = src; src = dst; dst = t;
    }
    __syncthreads();
    #pragma unroll
    for (int k = 0; k < 2; ++k) {
        int i = tid + k * 1024;
        unsigned int c = src[i];
        unsigned int cn = (i < 2047) ? src[i + 1] : 0u;
        if (c >= KSEL && cn < KSEL)
            selinfo[b] = make_uint4((unsigned int)i, cn, KSEL - cn, 0u);
    }
}

// -------- Kernel C: gather all keys with bin >= threshold bin (block-local compaction) --------
__global__ __launch_bounds__(256) void k_gather(const float* __restrict__ cls,
                                                const uint4* __restrict__ selinfo,
                                                unsigned long long* __restrict__ cand,
                                                unsigned int* __restrict__ ccnt) {
    int b = blockIdx.y, part = blockIdx.x, tid = threadIdx.x;
    unsigned int bin = selinfo[b].x;
    __shared__ unsigned long long lbuf[1024];
    __shared__ unsigned int lcnt, gbase;
    if (tid == 0) lcnt = 0u;
    __syncthreads();
    const float4* base4 = (const float4*)(cls + (size_t)b * NTOT);
    const int n4 = NTOT / 4;
    int per = (n4 + GSPLIT - 1) / GSPLIT;
    int lo = part * per, hi = lo + per;
    if (hi > n4) hi = n4;
    for (int i = lo + tid; i < hi; i += 256) {
        float4 v = base4[i];
        float vals[4] = {v.x, v.y, v.z, v.w};
        int idx0 = i * 4;
        #pragma unroll
        for (int q = 0; q < 4; ++q) {
            unsigned int u = xform(vals[q]);
            if ((u >> 21) >= bin) {
                int idx = idx0 + q;
                int a = idx / HWSZ;
                int hw = idx - a * HWSZ;
                unsigned int n = (unsigned int)(hw * NA + a);
                unsigned int pos = atomicAdd(&lcnt, 1u);
                if (pos < 1024u)
                    lbuf[pos] = ((unsigned long long)u << 32) | (unsigned long long)(~n);
            }
        }
    }
    __syncthreads();
    if (tid == 0) {
        unsigned int c = lcnt < 1024u ? lcnt : 1024u;
        gbase = atomicAdd(&ccnt[b], c);
    }
    __syncthreads();
    unsigned int c = lcnt < 1024u ? lcnt : 1024u;
    unsigned int gb = gbase;
    for (unsigned int i = tid; i < c; i += 256) {
        unsigned int p = gb + i;
        if (p < CANDCAP) cand[(size_t)b * CANDCAP + p] = lbuf[i];
    }
}

// -------- Kernel D: refine threshold + compact + bitonic sort (desc) + box decode --------
__global__ __launch_bounds__(1024) void k_sort_decode(
        const unsigned long long* __restrict__ cand,
        const unsigned int* __restrict__ ccnt,
        const uint4* __restrict__ selinfo,
        const float* __restrict__ regs,
        const float* __restrict__ anchors,
        const int* __restrict__ img_h,
        const int* __restrict__ img_w,
        float* __restrict__ out_scores,
        float4* __restrict__ boxes_ws,
        unsigned int* __restrict__ valid_ws) {
    int b = blockIdx.x;
    int tid = threadIdx.x;
    __shared__ unsigned long long arr[BUFCAP];
    __shared__ unsigned int sa[2048], sb[2048];
    __shared__ unsigned int acnt, shT;
    uint4 si = selinfo[b];
    unsigned int bin = si.x, krem = si.z;
    unsigned int m = ccnt[b];
    if (m > CANDCAP) m = CANDCAP;
    const unsigned long long* cb = cand + (size_t)b * CANDCAP;

    // sub-bin histogram (bits [20:10]) of in-bin candidates
    sa[tid] = 0u; sa[tid + 1024] = 0u;
    if (tid == 0) acnt = 0u;
    __syncthreads();
    for (unsigned int i = tid; i < m; i += 1024) {
        unsigned int u = (unsigned int)(cb[i] >> 32);
        if ((u >> 21) == bin) atomicAdd(&sa[(u >> 10) & 2047u], 1u);
    }
    // suffix scan
    unsigned int* src = sa; unsigned int* dst = sb;
    for (int d = 1; d < 2048; d <<= 1) {
        __syncthreads();
        dst[tid] = src[tid] + ((tid + d < 2048) ? src[tid + d] : 0u);
        int i2 = tid + 1024;
        dst[i2] = src[i2] + ((i2 + d < 2048) ? src[i2 + d] : 0u);
        unsigned int* t = src; src = dst; dst = t;
    }
    __syncthreads();
    #pragma unroll
    for (int k = 0; k < 2; ++k) {
        int i = tid + k * 1024;
        unsigned int c = src[i];
        unsigned int cn = (i < 2047) ? src[i + 1] : 0u;
        if (c >= krem && cn < krem)
            shT = (bin << 21) | ((unsigned int)i << 10);
    }
    __syncthreads();
    unsigned int T = shT;

    // compact keys >= T into arr via wave-ballot (+1 LDS atomic per wave-iter)
    int lane = tid & 63;
    unsigned long long lmask = (1ULL << lane) - 1ULL;
    unsigned int mr = (m + 1023u) & ~1023u;
    for (unsigned int i = tid; i < mr; i += 1024) {
        bool pred = false;
        unsigned long long key = 0ULL;
        if (i < m) {
            key = cb[i];
            pred = ((unsigned int)(key >> 32)) >= T;
        }
        unsigned long long mask = __ballot(pred);
        unsigned int cw = (unsigned int)__popcll(mask);
        unsigned int base = 0u;
        if (lane == 0 && cw) base = atomicAdd(&acnt, cw);
        base = __shfl(base, 0, 64);
        if (pred) {
            unsigned int pos = base + (unsigned int)__popcll(mask & lmask);
            if (pos < BUFCAP) arr[pos] = key;
        }
    }
    __syncthreads();
    unsigned int total = acnt < BUFCAP ? acnt : BUFCAP;
    for (unsigned int i = tid; i < BUFCAP; i += 1024)
        if (i >= total) arr[i] = 0ULL;
    __syncthreads();

    // bitonic sort, descending by packed key
    for (int k = 2; k <= BUFCAP; k <<= 1) {
        for (int j = k >> 1; j > 0; j >>= 1) {
            for (int i = tid; i < BUFCAP; i += 1024) {
                int ixj = i ^ j;
                if (ixj > i) {
                    unsigned long long x = arr[i], y = arr[ixj];
                    bool up = (i & k) == 0;
                    if (up ? (x < y) : (x > y)) { arr[i] = y; arr[ixj] = x; }
                }
            }
            __syncthreads();
        }
    }

    int hv = img_h[0];
    int wv = img_w[0];
    float himg = (hv > 0 && hv < 100000) ? (float)hv : __int_as_float(hv);
    float wimg = (wv > 0 && wv < 100000) ? (float)wv : __int_as_float(wv);

    for (int r = tid; r < KSEL; r += 1024) {
        unsigned long long packed = arr[r];
        size_t o = (size_t)b * KSEL + r;
        if (packed == 0ULL) {
            out_scores[o] = 0.f;
            boxes_ws[o] = make_float4(0.f, 0.f, 0.f, 0.f);
            valid_ws[o] = 0u;
            continue;
        }
        unsigned int u = (unsigned int)(packed >> 32);
        unsigned int n = ~((unsigned int)packed);
        unsigned int bits = (u & 0x80000000u) ? (u & 0x7FFFFFFFu) : ~u;
        float score = __uint_as_float(bits);
        int a = (int)(n % NA);
        int hw = (int)(n / NA);
        const float* rp = regs + ((size_t)b * (4 * NA) + 4 * a) * HWSZ + hw;
        float dx = rp[0 * HWSZ];
        float dy = rp[1 * HWSZ];
        float dh = rp[2 * HWSZ];
        float dw = rp[3 * HWSZ];
        const float* ap = anchors + ((size_t)b * NTOT + n) * 4;
        float ax1 = ap[0], ay1 = ap[1], ax2 = ap[2], ay2 = ap[3];
        float ahh = ay2 - ay1;
        float aww = ax2 - ax1;
        float cx = aww * 0.5f;
        float cy = ahh * 0.5f;
        float px = cx + dx * aww;
        float py = cy + dy * ahh;
        dh = fminf(dh, LOG_MAX_F);
        dw = fminf(dw, LOG_MAX_F);
        float ph = expf(dh) * ahh;
        float pw = expf(dw) * aww;
        float x1 = px - pw * 0.5f;
        float y1 = py - ph * 0.5f;
        float x2 = px + pw * 0.5f;
        float y2 = py + ph * 0.5f;
        float bwv = fminf(fmaxf(x2, 0.f), wimg) - fminf(fmaxf(x1, 0.f), wimg);
        float bhv = fminf(fmaxf(y2, 0.f), himg) - fminf(fmaxf(y1, 0.f), himg);
        unsigned int valid = (bwv >= 16.f && bhv >= 16.f) ? 1u : 0u;
        out_scores[o] = score;
        boxes_ws[o] = make_float4(x1, y1, x2, y2);
        valid_ws[o] = valid;
    }
}

// -------- Kernel 3: suppression bitmask matrix (rows x 64-col words) --------
__global__ __launch_bounds__(64) void k_supmat(const float4* __restrict__ boxes_ws,
                                               unsigned long long* __restrict__ sup) {
    int ct = blockIdx.x;
    int rt = blockIdx.y;
    int b  = blockIdx.z;
    int tid = threadIdx.x;
    __shared__ float4 colbox[64];
    int j0 = ct * 64;
    int jl = j0 + tid;
    colbox[tid] = (jl < KSEL) ? boxes_ws[(size_t)b * KSEL + jl]
                              : make_float4(0.f, 0.f, 0.f, 0.f);
    __syncthreads();
    int i = rt * 64 + tid;
    if (i >= KSEL) return;
    float4 bi = boxes_ws[(size_t)b * KSEL + i];
    float area_i = (bi.z - bi.x) * (bi.w - bi.y);
    unsigned long long word = 0ULL;
    #pragma unroll 8
    for (int jj = 0; jj < 64; ++jj) {
        int j = j0 + jj;
        float4 bj = colbox[jj];
        float area_j = (bj.z - bj.x) * (bj.w - bj.y);
        float ix1 = fmaxf(bi.x, bj.x);
        float iy1 = fmaxf(bi.y, bj.y);
        float ix2 = fminf(bi.z, bj.z);
        float iy2 = fminf(bi.w, bj.w);
        float iw = fmaxf(ix2 - ix1, 0.f);
        float ih = fmaxf(iy2 - iy1, 0.f);
        float inter = iw * ih;
        float uni = area_i + area_j - inter;
        float iou = inter / fmaxf(uni, 1e-6f);
        bool s = (j > i) && (j < KSEL) && (iou > 0.7f);
        if (s) word |= (1ULL << jj);
    }
    sup[((size_t)b * KSEL + i) * 32 + ct] = word;
}

// -------- Kernel 4: word-tile greedy scan (1 wave / batch) + outputs --------
__global__ __launch_bounds__(64) void k_nms_scan(const unsigned long long* __restrict__ sup,
                                                 const unsigned int* __restrict__ valid_ws,
                                                 const float4* __restrict__ boxes_ws,
                                                 float* __restrict__ out_boxes,
                                                 float* __restrict__ out_keep) {
    int b = blockIdx.x;
    int lane = threadIdx.x;
    unsigned long long kw = 0ULL;   // lane<32 holds keep-word `lane`
    if (lane < 32) {
        const uint4* vv = (const uint4*)(valid_ws + (size_t)b * KSEL);
        #pragma unroll 4
        for (int q = 0; q < 16; ++q) {
            uint4 x = vv[lane * 16 + q];
            int base = q * 4;
            if (x.x) kw |= 1ULL << (base + 0);
            if (x.y) kw |= 1ULL << (base + 1);
            if (x.z) kw |= 1ULL << (base + 2);
            if (x.w) kw |= 1ULL << (base + 3);
        }
        if (lane == 31) kw &= 0xFFFFULL;   // rows 2000..2047 invalid
    }
    const unsigned long long* srow = sup + (size_t)b * KSEL * 32;
    __shared__ unsigned long long tile[64];

    for (int w = 0; w < 32; ++w) {
        int r = w * 64 + lane;
        unsigned long long diag = (r < KSEL) ? srow[(size_t)r * 32 + w] : 0ULL;
        unsigned long long cur = __shfl(kw, w, 64);
        tile[lane] = diag;
        __syncthreads();
        #pragma unroll 16
        for (int bit = 0; bit < 64; ++bit) {
            unsigned long long d = tile[bit];
            if ((cur >> bit) & 1ULL) cur &= ~d;
        }
        if (lane == w) kw = cur;
        #pragma unroll 4
        for (int bit = 0; bit < 64; ++bit) {
            if ((cur >> bit) & 1ULL) {
                int i = w * 64 + bit;
                if (lane < 32) kw &= ~srow[(size_t)i * 32 + lane];
            }
        }
        __syncthreads();
    }

    __shared__ unsigned long long kws[32];
    if (lane < 32) kws[lane] = kw;
    __syncthreads();
    for (int r = lane; r < KSEL; r += 64) {
        float kf = (float)((kws[r >> 6] >> (r & 63)) & 1ULL);
        size_t o = (size_t)b * KSEL + r;
        out_keep[o] = kf;
        float4 bx = boxes_ws[o];
        float* ob = out_boxes + o * 4;
        ob[0] = bx.x * kf;
        ob[1] = bx.y * kf;
        ob[2] = bx.z * kf;
        ob[3] = bx.w * kf;
    }
}

extern "C" void kernel_launch(void* const* d_in, const int* in_sizes, int n_in,
                              void* d_out, int out_size, void* d_ws, size_t ws_size,
                              hipStream_t stream) {
    const float* cls     = (const float*)d_in[0];
    const float* regs    = (const float*)d_in[1];
    const float* anchors = (const float*)d_in[2];
    const int*   img_h   = (const int*)d_in[3];
    const int*   img_w   = (const int*)d_in[4];

    float* out = (float*)d_out;
    float* out_boxes  = out;            // 8*2000*4
    float* out_scores = out + 64000;    // 8*2000
    float* out_keep   = out + 80000;    // 8*2000

    char* ws = (char*)d_ws;
    unsigned int* hist1      = (unsigned int*)(ws + OFF_H1);
    unsigned int* ccnt       = (unsigned int*)(ws + OFF_CCNT);
    uint4* selinfo           = (uint4*)(ws + OFF_SEL);
    float4* boxes_ws         = (float4*)(ws + OFF_BOX);
    unsigned int* valid_ws   = (unsigned int*)(ws + OFF_VALID);
    unsigned long long* sup  = (unsigned long long*)(ws + OFF_SUP);
    unsigned long long* cand = (unsigned long long*)(ws + OFF_CAND);

    hipMemsetAsync(ws, 0, ZR_BYTES, stream);
    k_hist1<<<dim3(GSPLIT, NBATCH), 256, 0, stream>>>(cls, hist1);
    k_scan1<<<NBATCH, 1024, 0, stream>>>(hist1, selinfo);
    k_gather<<<dim3(GSPLIT, NBATCH), 256, 0, stream>>>(cls, selinfo, cand, ccnt);
    k_sort_decode<<<NBATCH, 1024, 0, stream>>>(cand, ccnt, selinfo, regs, anchors,
                                               img_h, img_w, out_scores, boxes_ws, valid_ws);
    k_supmat<<<dim3(32, 32, NBATCH), 64, 0, stream>>>(boxes_ws, sup);
    k_nms_scan<<<NBATCH, 64, 0, stream>>>(sup, valid_ws, boxes_ws, out_boxes, out_keep);
}

// Round 4
// 343.227 us; speedup vs baseline: 1.8268x; 1.0682x over previous
//
#include <hip/hip_runtime.h>

// Problem constants (B=8, A=3, H=200, W=304)
#define HWSZ 60800      // H*W
#define NA 3
#define NTOT 182400     // A*H*W
#define KSEL 2000
#define BUFCAP 2048
#define CANDCAP 8192
#define NBATCH 8
#define GSPLIT 128
#define LOG_MAX_F 4.135166556742356f   // log(1000/16) rounded to fp32

// ---- workspace layout (bytes) ----
#define OFF_H1    0          // 8*2048*4 = 65536
#define OFF_CCNT  65536      // 8*4 = 32
#define ZR_BYTES  65568      // zeroes H1 + CCNT
#define OFF_SEL   65568      // 8*16 = 128 (16B aligned)
#define OFF_BOX   65696      // 8*2000*16 = 256000 (16B aligned)
#define OFF_VALID 321696     // 8*2000*4 = 64000
#define OFF_SUP   385696     // 8*2000*32*8 = 4096000 (8B aligned)
#define OFF_CAND  385696     // overlay on sup (disjoint lifetime): 8*8192*8 = 524288

__device__ __forceinline__ unsigned int xform(float f) {
    unsigned int b = __float_as_uint(f);
    return b ^ ((unsigned int)((int)b >> 31) | 0x80000000u);  // monotonic float->uint
}

// ---------------- Kernel A: per-batch 2048-bin hist of top-11 key bits ----------------
__global__ __launch_bounds__(256) void k_hist1(const float* __restrict__ cls,
                                               unsigned int* __restrict__ hist1) {
    int b = blockIdx.y, part = blockIdx.x, tid = threadIdx.x;
    __shared__ unsigned int h[2048];
    for (int i = tid; i < 2048; i += 256) h[i] = 0u;
    __syncthreads();
    const float4* base4 = (const float4*)(cls + (size_t)b * NTOT);
    const int n4 = NTOT / 4;                    // 45600
    int per = (n4 + GSPLIT - 1) / GSPLIT;
    int lo = part * per, hi = lo + per;
    if (hi > n4) hi = n4;
    for (int i = lo + tid; i < hi; i += 256) {
        float4 v = base4[i];
        atomicAdd(&h[xform(v.x) >> 21], 1u);
        atomicAdd(&h[xform(v.y) >> 21], 1u);
        atomicAdd(&h[xform(v.z) >> 21], 1u);
        atomicAdd(&h[xform(v.w) >> 21], 1u);
    }
    __syncthreads();
    unsigned int* gh = hist1 + b * 2048;
    for (int i = tid; i < 2048; i += 256)
        if (h[i]) atomicAdd(&gh[i], h[i]);
}

// ---------------- Kernel B: suffix-scan hist1, find threshold bin ----------------
__global__ __launch_bounds__(1024) void k_scan1(const unsigned int* __restrict__ hist1,
                                                uint4* __restrict__ selinfo) {
    int b = blockIdx.x, tid = threadIdx.x;
    __shared__ unsigned int sa[2048], sb[2048];
    const unsigned int* h = hist1 + b * 2048;
    sa[tid] = h[tid];
    sa[tid + 1024] = h[tid + 1024];
    unsigned int* src = sa; unsigned int* dst = sb;
    for (int d = 1; d < 2048; d <<= 1) {
        __syncthreads();
        dst[tid] = src[tid] + ((tid + d < 2048) ? src[tid + d] : 0u);
        int i2 = tid + 1024;
        dst[i2] = src[i2] + ((i2 + d < 2048) ? src[i2 + d] : 0u);
        unsigned int* t = src; src = dst; dst = t;
    }
    __syncthreads();
    #pragma unroll
    for (int k = 0; k < 2; ++k) {
        int i = tid + k * 1024;
        unsigned int c = src[i];
        unsigned int cn = (i < 2047) ? src[i + 1] : 0u;
        if (c >= KSEL && cn < KSEL)
            selinfo[b] = make_uint4((unsigned int)i, cn, KSEL - cn, 0u);
    }
}

// -------- Kernel C: gather all keys with bin >= threshold bin (block-local compaction) --------
__global__ __launch_bounds__(256) void k_gather(const float* __restrict__ cls,
                                                const uint4* __restrict__ selinfo,
                                                unsigned long long* __restrict__ cand,
                                                unsigned int* __restrict__ ccnt) {
    int b = blockIdx.y, part = blockIdx.x, tid = threadIdx.x;
    unsigned int bin = selinfo[b].x;
    __shared__ unsigned long long lbuf[1024];
    __shared__ unsigned int lcnt, gbase;
    if (tid == 0) lcnt = 0u;
    __syncthreads();
    const float4* base4 = (const float4*)(cls + (size_t)b * NTOT);
    const int n4 = NTOT / 4;
    int per = (n4 + GSPLIT - 1) / GSPLIT;
    int lo = part * per, hi = lo + per;
    if (hi > n4) hi = n4;
    for (int i = lo + tid; i < hi; i += 256) {
        float4 v = base4[i];
        float vals[4] = {v.x, v.y, v.z, v.w};
        int idx0 = i * 4;
        #pragma unroll
        for (int q = 0; q < 4; ++q) {
            unsigned int u = xform(vals[q]);
            if ((u >> 21) >= bin) {
                int idx = idx0 + q;
                int a = idx / HWSZ;
                int hw = idx - a * HWSZ;
                unsigned int n = (unsigned int)(hw * NA + a);
                unsigned int pos = atomicAdd(&lcnt, 1u);
                if (pos < 1024u)
                    lbuf[pos] = ((unsigned long long)u << 32) | (unsigned long long)(~n);
            }
        }
    }
    __syncthreads();
    if (tid == 0) {
        unsigned int c = lcnt < 1024u ? lcnt : 1024u;
        gbase = atomicAdd(&ccnt[b], c);
    }
    __syncthreads();
    unsigned int c = lcnt < 1024u ? lcnt : 1024u;
    unsigned int gb = gbase;
    for (unsigned int i = tid; i < c; i += 256) {
        unsigned int p = gb + i;
        if (p < CANDCAP) cand[(size_t)b * CANDCAP + p] = lbuf[i];
    }
}

// -------- Kernel D: refine threshold + compact + bitonic sort (desc) + box decode --------
__global__ __launch_bounds__(1024) void k_sort_decode(
        const unsigned long long* __restrict__ cand,
        const unsigned int* __restrict__ ccnt,
        const uint4* __restrict__ selinfo,
        const float* __restrict__ regs,
        const float* __restrict__ anchors,
        const int* __restrict__ img_h,
        const int* __restrict__ img_w,
        float* __restrict__ out_scores,
        float4* __restrict__ boxes_ws,
        unsigned int* __restrict__ valid_ws) {
    int b = blockIdx.x;
    int tid = threadIdx.x;
    __shared__ unsigned long long arr[BUFCAP];
    __shared__ unsigned int sa[2048], sb[2048];
    __shared__ unsigned int acnt, shT;
    uint4 si = selinfo[b];
    unsigned int bin = si.x, krem = si.z;
    unsigned int m = ccnt[b];
    if (m > CANDCAP) m = CANDCAP;
    const unsigned long long* cb = cand + (size_t)b * CANDCAP;

    // sub-bin histogram (bits [20:10]) of in-bin candidates
    sa[tid] = 0u; sa[tid + 1024] = 0u;
    if (tid == 0) acnt = 0u;
    __syncthreads();
    for (unsigned int i = tid; i < m; i += 1024) {
        unsigned int u = (unsigned int)(cb[i] >> 32);
        if ((u >> 21) == bin) atomicAdd(&sa[(u >> 10) & 2047u], 1u);
    }
    // suffix scan
    unsigned int* src = sa; unsigned int* dst = sb;
    for (int d = 1; d < 2048; d <<= 1) {
        __syncthreads();
        dst[tid] = src[tid] + ((tid + d < 2048) ? src[tid + d] : 0u);
        int i2 = tid + 1024;
        dst[i2] = src[i2] + ((i2 + d < 2048) ? src[i2 + d] : 0u);
        unsigned int* t = src; src = dst; dst = t;
    }
    __syncthreads();
    #pragma unroll
    for (int k = 0; k < 2; ++k) {
        int i = tid + k * 1024;
        unsigned int c = src[i];
        unsigned int cn = (i < 2047) ? src[i + 1] : 0u;
        if (c >= krem && cn < krem)
            shT = (bin << 21) | ((unsigned int)i << 10);
    }
    __syncthreads();
    unsigned int T = shT;

    // compact keys >= T into arr via wave-ballot (+1 LDS atomic per wave-iter)
    int lane = tid & 63;
    unsigned long long lmask = (1ULL << lane) - 1ULL;
    unsigned int mr = (m + 1023u) & ~1023u;
    for (unsigned int i = tid; i < mr; i += 1024) {
        bool pred = false;
        unsigned long long key = 0ULL;
        if (i < m) {
            key = cb[i];
            pred = ((unsigned int)(key >> 32)) >= T;
        }
        unsigned long long mask = __ballot(pred);
        unsigned int cw = (unsigned int)__popcll(mask);
        unsigned int base = 0u;
        if (lane == 0 && cw) base = atomicAdd(&acnt, cw);
        base = __shfl(base, 0, 64);
        if (pred) {
            unsigned int pos = base + (unsigned int)__popcll(mask & lmask);
            if (pos < BUFCAP) arr[pos] = key;
        }
    }
    __syncthreads();
    unsigned int total = acnt < BUFCAP ? acnt : BUFCAP;
    for (unsigned int i = tid; i < BUFCAP; i += 1024)
        if (i >= total) arr[i] = 0ULL;
    __syncthreads();

    // bitonic sort, descending by packed key
    for (int k = 2; k <= BUFCAP; k <<= 1) {
        for (int j = k >> 1; j > 0; j >>= 1) {
            for (int i = tid; i < BUFCAP; i += 1024) {
                int ixj = i ^ j;
                if (ixj > i) {
                    unsigned long long x = arr[i], y = arr[ixj];
                    bool up = (i & k) == 0;
                    if (up ? (x < y) : (x > y)) { arr[i] = y; arr[ixj] = x; }
                }
            }
            __syncthreads();
        }
    }

    int hv = img_h[0];
    int wv = img_w[0];
    float himg = (hv > 0 && hv < 100000) ? (float)hv : __int_as_float(hv);
    float wimg = (wv > 0 && wv < 100000) ? (float)wv : __int_as_float(wv);

    for (int r = tid; r < KSEL; r += 1024) {
        unsigned long long packed = arr[r];
        size_t o = (size_t)b * KSEL + r;
        if (packed == 0ULL) {
            out_scores[o] = 0.f;
            boxes_ws[o] = make_float4(0.f, 0.f, 0.f, 0.f);
            valid_ws[o] = 0u;
            continue;
        }
        unsigned int u = (unsigned int)(packed >> 32);
        unsigned int n = ~((unsigned int)packed);
        unsigned int bits = (u & 0x80000000u) ? (u & 0x7FFFFFFFu) : ~u;
        float score = __uint_as_float(bits);
        int a = (int)(n % NA);
        int hw = (int)(n / NA);
        const float* rp = regs + ((size_t)b * (4 * NA) + 4 * a) * HWSZ + hw;
        float dx = rp[0 * HWSZ];
        float dy = rp[1 * HWSZ];
        float dh = rp[2 * HWSZ];
        float dw = rp[3 * HWSZ];
        const float* ap = anchors + ((size_t)b * NTOT + n) * 4;
        float ax1 = ap[0], ay1 = ap[1], ax2 = ap[2], ay2 = ap[3];
        float ahh = ay2 - ay1;
        float aww = ax2 - ax1;
        float cx = aww * 0.5f;
        float cy = ahh * 0.5f;
        float px = cx + dx * aww;
        float py = cy + dy * ahh;
        dh = fminf(dh, LOG_MAX_F);
        dw = fminf(dw, LOG_MAX_F);
        float ph = expf(dh) * ahh;
        float pw = expf(dw) * aww;
        float x1 = px - pw * 0.5f;
        float y1 = py - ph * 0.5f;
        float x2 = px + pw * 0.5f;
        float y2 = py + ph * 0.5f;
        float bwv = fminf(fmaxf(x2, 0.f), wimg) - fminf(fmaxf(x1, 0.f), wimg);
        float bhv = fminf(fmaxf(y2, 0.f), himg) - fminf(fmaxf(y1, 0.f), himg);
        unsigned int valid = (bwv >= 16.f && bhv >= 16.f) ? 1u : 0u;
        out_scores[o] = score;
        boxes_ws[o] = make_float4(x1, y1, x2, y2);
        valid_ws[o] = valid;
    }
}

// -------- Kernel 3: suppression bitmask matrix (rows x 64-col words), 256 thr --------
__global__ __launch_bounds__(256) void k_supmat(const float4* __restrict__ boxes_ws,
                                                unsigned long long* __restrict__ sup) {
    int ct = blockIdx.x;    // col tile 0..31
    int rt = blockIdx.y;    // row super-tile 0..7 (256 rows each)
    int b  = blockIdx.z;
    int tid = threadIdx.x;
    __shared__ float4 colbox[64];
    int j0 = ct * 64;
    if (tid < 64) {
        int jl = j0 + tid;
        colbox[tid] = (jl < KSEL) ? boxes_ws[(size_t)b * KSEL + jl]
                                  : make_float4(0.f, 0.f, 0.f, 0.f);
    }
    __syncthreads();
    int i = rt * 256 + tid;
    if (i >= KSEL) return;
    float4 bi = boxes_ws[(size_t)b * KSEL + i];
    float area_i = (bi.z - bi.x) * (bi.w - bi.y);
    unsigned long long word = 0ULL;
    #pragma unroll 8
    for (int jj = 0; jj < 64; ++jj) {
        int j = j0 + jj;
        float4 bj = colbox[jj];
        float area_j = (bj.z - bj.x) * (bj.w - bj.y);
        float ix1 = fmaxf(bi.x, bj.x);
        float iy1 = fmaxf(bi.y, bj.y);
        float ix2 = fminf(bi.z, bj.z);
        float iy2 = fminf(bi.w, bj.w);
        float iw = fmaxf(ix2 - ix1, 0.f);
        float ih = fmaxf(iy2 - iy1, 0.f);
        float inter = iw * ih;
        float uni = area_i + area_j - inter;
        float iou = inter / fmaxf(uni, 1e-6f);
        bool s = (j > i) && (j < KSEL) && (iou > 0.7f);
        if (s) word |= (1ULL << jj);
    }
    sup[((size_t)b * KSEL + i) * 32 + ct] = word;
}

// -------- Kernel 4: word-tile greedy scan, bulk-prefetched tiles, 1024 thr --------
__global__ __launch_bounds__(1024) void k_nms_scan(const unsigned long long* __restrict__ sup,
                                                   const unsigned int* __restrict__ valid_ws,
                                                   const float4* __restrict__ boxes_ws,
                                                   float* __restrict__ out_boxes,
                                                   float* __restrict__ out_keep) {
    int b = blockIdx.x;
    int tid = threadIdx.x;
    int lane = tid & 63;
    __shared__ unsigned long long kws[32];
    __shared__ unsigned long long tile[2048];   // [row 0..63][word 0..31]
    __shared__ unsigned int accw[64];           // lo/hi halves per word
    const unsigned long long* srow = sup + (size_t)b * KSEL * 32;

    if (tid < 32) {
        unsigned long long kw = 0ULL;
        const uint4* vv = (const uint4*)(valid_ws + (size_t)b * KSEL);
        #pragma unroll 4
        for (int q = 0; q < 16; ++q) {
            uint4 x = vv[tid * 16 + q];
            int base = q * 4;
            if (x.x) kw |= 1ULL << (base + 0);
            if (x.y) kw |= 1ULL << (base + 1);
            if (x.z) kw |= 1ULL << (base + 2);
            if (x.w) kw |= 1ULL << (base + 3);
        }
        if (tid == 31) kw &= 0xFFFFULL;   // rows 2000..2047 invalid
        kws[tid] = kw;
    }
    if (tid < 64) accw[tid] = 0u;

    // prefetch tile 0 (tile w entry e lives at srow[w*2048 + e]; rows < KSEL)
    unsigned long long r0 = srow[tid];
    unsigned long long r1 = srow[tid + 1024];

    for (int w = 0; w < 32; ++w) {
        tile[tid] = r0;
        tile[tid + 1024] = r1;
        __syncthreads();                        // tile ready; kws/accw settled
        if (w < 31) {
            int base = (w + 1) * 2048;
            int row0 = (w + 1) * 64 + (tid >> 5);
            int row1 = row0 + 32;
            r0 = (row0 < KSEL) ? srow[base + tid] : 0ULL;
            r1 = (row1 < KSEL) ? srow[base + tid + 1024] : 0ULL;
        }
        // 64-step greedy chain within word w (redundant in all threads; broadcast reads)
        unsigned long long cur = kws[w];
        #pragma unroll 16
        for (int bit = 0; bit < 64; ++bit) {
            unsigned long long d = tile[bit * 32 + w];
            unsigned long long msk = 0ULL - ((cur >> bit) & 1ULL);
            cur &= ~(d & msk);
        }
        // masked OR-reduce of kept rows' suppression words
        {
            int r = tid >> 5;                   // row 0..31; +32 for second entry
            unsigned long long v = 0ULL;
            if ((cur >> r) & 1ULL) v = tile[tid];
            if ((cur >> (r + 32)) & 1ULL) v |= tile[tid + 1024];
            v |= __shfl_xor(v, 32, 64);         // fold r-pairs; lanes<32 hold per-word OR
            if (lane < 32 && v) {
                atomicOr(&accw[lane * 2], (unsigned int)v);
                atomicOr(&accw[lane * 2 + 1], (unsigned int)(v >> 32));
            }
        }
        if (tid == 0) kws[w] = cur;
        __syncthreads();                        // accw complete; tile free to overwrite
        if (tid < 32) {
            unsigned long long a = ((unsigned long long)accw[tid * 2 + 1] << 32)
                                   | (unsigned long long)accw[tid * 2];
            kws[tid] &= ~a;                     // no-op for words <= w (upper-triangular)
            accw[tid * 2] = 0u;
            accw[tid * 2 + 1] = 0u;
        }
    }
    __syncthreads();

    for (int r = tid; r < KSEL; r += 1024) {
        float kf = (float)((kws[r >> 6] >> (r & 63)) & 1ULL);
        size_t o = (size_t)b * KSEL + r;
        out_keep[o] = kf;
        float4 bx = boxes_ws[o];
        float* ob = out_boxes + o * 4;
        ob[0] = bx.x * kf;
        ob[1] = bx.y * kf;
        ob[2] = bx.z * kf;
        ob[3] = bx.w * kf;
    }
}

extern "C" void kernel_launch(void* const* d_in, const int* in_sizes, int n_in,
                              void* d_out, int out_size, void* d_ws, size_t ws_size,
                              hipStream_t stream) {
    const float* cls     = (const float*)d_in[0];
    const float* regs    = (const float*)d_in[1];
    const float* anchors = (const float*)d_in[2];
    const int*   img_h   = (const int*)d_in[3];
    const int*   img_w   = (const int*)d_in[4];

    float* out = (float*)d_out;
    float* out_boxes  = out;            // 8*2000*4
    float* out_scores = out + 64000;    // 8*2000
    float* out_keep   = out + 80000;    // 8*2000

    char* ws = (char*)d_ws;
    unsigned int* hist1      = (unsigned int*)(ws + OFF_H1);
    unsigned int* ccnt       = (unsigned int*)(ws + OFF_CCNT);
    uint4* selinfo           = (uint4*)(ws + OFF_SEL);
    float4* boxes_ws         = (float4*)(ws + OFF_BOX);
    unsigned int* valid_ws   = (unsigned int*)(ws + OFF_VALID);
    unsigned long long* sup  = (unsigned long long*)(ws + OFF_SUP);
    unsigned long long* cand = (unsigned long long*)(ws + OFF_CAND);

    hipMemsetAsync(ws, 0, ZR_BYTES, stream);
    k_hist1<<<dim3(GSPLIT, NBATCH), 256, 0, stream>>>(cls, hist1);
    k_scan1<<<NBATCH, 1024, 0, stream>>>(hist1, selinfo);
    k_gather<<<dim3(GSPLIT, NBATCH), 256, 0, stream>>>(cls, selinfo, cand, ccnt);
    k_sort_decode<<<NBATCH, 1024, 0, stream>>>(cand, ccnt, selinfo, regs, anchors,
                                               img_h, img_w, out_scores, boxes_ws, valid_ws);
    k_supmat<<<dim3(32, 8, NBATCH), 256, 0, stream>>>(boxes_ws, sup);
    k_nms_scan<<<NBATCH, 1024, 0, stream>>>(sup, valid_ws, boxes_ws, out_boxes, out_keep);
}

// Round 5
// 279.497 us; speedup vs baseline: 2.2433x; 1.2280x over previous
//
#include <hip/hip_runtime.h>

// Problem constants (B=8, A=3, H=200, W=304)
#define HWSZ 60800      // H*W
#define NA 3
#define NTOT 182400     // A*H*W
#define KSEL 2000
#define BUFCAP 2048
#define CANDCAP 8192
#define NBATCH 8
#define GSPLIT 128
#define LOG_MAX_F 4.135166556742356f   // log(1000/16) rounded to fp32

// ---- workspace layout (bytes) ----
#define OFF_H1    0          // 8*2048*4 = 65536
#define OFF_CCNT  65536      // 8*4 = 32
#define ZR_BYTES  65568      // zeroes H1 + CCNT
#define OFF_SEL   65568      // 8*16 = 128 (16B aligned)
#define OFF_BOX   65696      // 8*2000*16 = 256000 (16B aligned)
#define OFF_VALID 321696     // 8*2000*4 = 64000
#define OFF_SUP   385696     // 8*2000*32*8 = 4096000 (8B aligned)
#define OFF_CAND  385696     // overlay on sup (disjoint lifetime): 8*8192*8 = 524288

__device__ __forceinline__ unsigned int xform(float f) {
    unsigned int b = __float_as_uint(f);
    return b ^ ((unsigned int)((int)b >> 31) | 0x80000000u);  // monotonic float->uint
}

// ---------------- Kernel A: per-batch 2048-bin hist of top-11 key bits ----------------
__global__ __launch_bounds__(256) void k_hist1(const float* __restrict__ cls,
                                               unsigned int* __restrict__ hist1) {
    int b = blockIdx.y, part = blockIdx.x, tid = threadIdx.x;
    __shared__ unsigned int h[2048];
    for (int i = tid; i < 2048; i += 256) h[i] = 0u;
    __syncthreads();
    const float4* base4 = (const float4*)(cls + (size_t)b * NTOT);
    const int n4 = NTOT / 4;                    // 45600
    int per = (n4 + GSPLIT - 1) / GSPLIT;
    int lo = part * per, hi = lo + per;
    if (hi > n4) hi = n4;
    for (int i = lo + tid; i < hi; i += 256) {
        float4 v = base4[i];
        atomicAdd(&h[xform(v.x) >> 21], 1u);
        atomicAdd(&h[xform(v.y) >> 21], 1u);
        atomicAdd(&h[xform(v.z) >> 21], 1u);
        atomicAdd(&h[xform(v.w) >> 21], 1u);
    }
    __syncthreads();
    unsigned int* gh = hist1 + b * 2048;
    for (int i = tid; i < 2048; i += 256)
        if (h[i]) atomicAdd(&gh[i], h[i]);
}

// ---------------- Kernel B: suffix-scan hist1, find threshold bin ----------------
__global__ __launch_bounds__(1024) void k_scan1(const unsigned int* __restrict__ hist1,
                                                uint4* __restrict__ selinfo) {
    int b = blockIdx.x, tid = threadIdx.x;
    __shared__ unsigned int sa[2048], sb[2048];
    const unsigned int* h = hist1 + b * 2048;
    sa[tid] = h[tid];
    sa[tid + 1024] = h[tid + 1024];
    unsigned int* src = sa; unsigned int* dst = sb;
    for (int d = 1; d < 2048; d <<= 1) {
        __syncthreads();
        dst[tid] = src[tid] + ((tid + d < 2048) ? src[tid + d] : 0u);
        int i2 = tid + 1024;
        dst[i2] = src[i2] + ((i2 + d < 2048) ? src[i2 + d] : 0u);
        unsigned int* t = src; src = dst; dst = t;
    }
    __syncthreads();
    #pragma unroll
    for (int k = 0; k < 2; ++k) {
        int i = tid + k * 1024;
        unsigned int c = src[i];
        unsigned int cn = (i < 2047) ? src[i + 1] : 0u;
        if (c >= KSEL && cn < KSEL)
            selinfo[b] = make_uint4((unsigned int)i, cn, KSEL - cn, 0u);
    }
}

// -------- Kernel C: gather all keys with bin >= threshold bin (block-local compaction) --------
__global__ __launch_bounds__(256) void k_gather(const float* __restrict__ cls,
                                                const uint4* __restrict__ selinfo,
                                                unsigned long long* __restrict__ cand,
                                                unsigned int* __restrict__ ccnt) {
    int b = blockIdx.y, part = blockIdx.x, tid = threadIdx.x;
    unsigned int bin = selinfo[b].x;
    __shared__ unsigned long long lbuf[1024];
    __shared__ unsigned int lcnt, gbase;
    if (tid == 0) lcnt = 0u;
    __syncthreads();
    const float4* base4 = (const float4*)(cls + (size_t)b * NTOT);
    const int n4 = NTOT / 4;
    int per = (n4 + GSPLIT - 1) / GSPLIT;
    int lo = part * per, hi = lo + per;
    if (hi > n4) hi = n4;
    for (int i = lo + tid; i < hi; i += 256) {
        float4 v = base4[i];
        float vals[4] = {v.x, v.y, v.z, v.w};
        int idx0 = i * 4;
        #pragma unroll
        for (int q = 0; q < 4; ++q) {
            unsigned int u = xform(vals[q]);
            if ((u >> 21) >= bin) {
                int idx = idx0 + q;
                int a = idx / HWSZ;
                int hw = idx - a * HWSZ;
                unsigned int n = (unsigned int)(hw * NA + a);
                unsigned int pos = atomicAdd(&lcnt, 1u);
                if (pos < 1024u)
                    lbuf[pos] = ((unsigned long long)u << 32) | (unsigned long long)(~n);
            }
        }
    }
    __syncthreads();
    if (tid == 0) {
        unsigned int c = lcnt < 1024u ? lcnt : 1024u;
        gbase = atomicAdd(&ccnt[b], c);
    }
    __syncthreads();
    unsigned int c = lcnt < 1024u ? lcnt : 1024u;
    unsigned int gb = gbase;
    for (unsigned int i = tid; i < c; i += 256) {
        unsigned int p = gb + i;
        if (p < CANDCAP) cand[(size_t)b * CANDCAP + p] = lbuf[i];
    }
}

// -------- Kernel D: refine threshold + compact + bitonic sort (desc) + box decode --------
__global__ __launch_bounds__(1024) void k_sort_decode(
        const unsigned long long* __restrict__ cand,
        const unsigned int* __restrict__ ccnt,
        const uint4* __restrict__ selinfo,
        const float* __restrict__ regs,
        const float* __restrict__ anchors,
        const int* __restrict__ img_h,
        const int* __restrict__ img_w,
        float* __restrict__ out_scores,
        float4* __restrict__ boxes_ws,
        unsigned int* __restrict__ valid_ws) {
    int b = blockIdx.x;
    int tid = threadIdx.x;
    __shared__ unsigned long long arr[BUFCAP];
    __shared__ unsigned int sa[2048], sb[2048];
    __shared__ unsigned int acnt, shT;
    uint4 si = selinfo[b];
    unsigned int bin = si.x, krem = si.z;
    unsigned int m = ccnt[b];
    if (m > CANDCAP) m = CANDCAP;
    const unsigned long long* cb = cand + (size_t)b * CANDCAP;

    // sub-bin histogram (bits [20:10]) of in-bin candidates
    sa[tid] = 0u; sa[tid + 1024] = 0u;
    if (tid == 0) acnt = 0u;
    __syncthreads();
    for (unsigned int i = tid; i < m; i += 1024) {
        unsigned int u = (unsigned int)(cb[i] >> 32);
        if ((u >> 21) == bin) atomicAdd(&sa[(u >> 10) & 2047u], 1u);
    }
    // suffix scan
    unsigned int* src = sa; unsigned int* dst = sb;
    for (int d = 1; d < 2048; d <<= 1) {
        __syncthreads();
        dst[tid] = src[tid] + ((tid + d < 2048) ? src[tid + d] : 0u);
        int i2 = tid + 1024;
        dst[i2] = src[i2] + ((i2 + d < 2048) ? src[i2 + d] : 0u);
        unsigned int* t = src; src = dst; dst = t;
    }
    __syncthreads();
    #pragma unroll
    for (int k = 0; k < 2; ++k) {
        int i = tid + k * 1024;
        unsigned int c = src[i];
        unsigned int cn = (i < 2047) ? src[i + 1] : 0u;
        if (c >= krem && cn < krem)
            shT = (bin << 21) | ((unsigned int)i << 10);
    }
    __syncthreads();
    unsigned int T = shT;

    // compact keys >= T into arr via wave-ballot (+1 LDS atomic per wave-iter)
    int lane = tid & 63;
    unsigned long long lmask = (1ULL << lane) - 1ULL;
    unsigned int mr = (m + 1023u) & ~1023u;
    for (unsigned int i = tid; i < mr; i += 1024) {
        bool pred = false;
        unsigned long long key = 0ULL;
        if (i < m) {
            key = cb[i];
            pred = ((unsigned int)(key >> 32)) >= T;
        }
        unsigned long long mask = __ballot(pred);
        unsigned int cw = (unsigned int)__popcll(mask);
        unsigned int base = 0u;
        if (lane == 0 && cw) base = atomicAdd(&acnt, cw);
        base = __shfl(base, 0, 64);
        if (pred) {
            unsigned int pos = base + (unsigned int)__popcll(mask & lmask);
            if (pos < BUFCAP) arr[pos] = key;
        }
    }
    __syncthreads();
    unsigned int total = acnt < BUFCAP ? acnt : BUFCAP;
    for (unsigned int i = tid; i < BUFCAP; i += 1024)
        if (i >= total) arr[i] = 0ULL;
    __syncthreads();

    // bitonic sort, descending by packed key
    for (int k = 2; k <= BUFCAP; k <<= 1) {
        for (int j = k >> 1; j > 0; j >>= 1) {
            for (int i = tid; i < BUFCAP; i += 1024) {
                int ixj = i ^ j;
                if (ixj > i) {
                    unsigned long long x = arr[i], y = arr[ixj];
                    bool up = (i & k) == 0;
                    if (up ? (x < y) : (x > y)) { arr[i] = y; arr[ixj] = x; }
                }
            }
            __syncthreads();
        }
    }

    int hv = img_h[0];
    int wv = img_w[0];
    float himg = (hv > 0 && hv < 100000) ? (float)hv : __int_as_float(hv);
    float wimg = (wv > 0 && wv < 100000) ? (float)wv : __int_as_float(wv);

    for (int r = tid; r < KSEL; r += 1024) {
        unsigned long long packed = arr[r];
        size_t o = (size_t)b * KSEL + r;
        if (packed == 0ULL) {
            out_scores[o] = 0.f;
            boxes_ws[o] = make_float4(0.f, 0.f, 0.f, 0.f);
            valid_ws[o] = 0u;
            continue;
        }
        unsigned int u = (unsigned int)(packed >> 32);
        unsigned int n = ~((unsigned int)packed);
        unsigned int bits = (u & 0x80000000u) ? (u & 0x7FFFFFFFu) : ~u;
        float score = __uint_as_float(bits);
        int a = (int)(n % NA);
        int hw = (int)(n / NA);
        const float* rp = regs + ((size_t)b * (4 * NA) + 4 * a) * HWSZ + hw;
        float dx = rp[0 * HWSZ];
        float dy = rp[1 * HWSZ];
        float dh = rp[2 * HWSZ];
        float dw = rp[3 * HWSZ];
        const float* ap = anchors + ((size_t)b * NTOT + n) * 4;
        float ax1 = ap[0], ay1 = ap[1], ax2 = ap[2], ay2 = ap[3];
        float ahh = ay2 - ay1;
        float aww = ax2 - ax1;
        float cx = aww * 0.5f;
        float cy = ahh * 0.5f;
        float px = cx + dx * aww;
        float py = cy + dy * ahh;
        dh = fminf(dh, LOG_MAX_F);
        dw = fminf(dw, LOG_MAX_F);
        float ph = expf(dh) * ahh;
        float pw = expf(dw) * aww;
        float x1 = px - pw * 0.5f;
        float y1 = py - ph * 0.5f;
        float x2 = px + pw * 0.5f;
        float y2 = py + ph * 0.5f;
        float bwv = fminf(fmaxf(x2, 0.f), wimg) - fminf(fmaxf(x1, 0.f), wimg);
        float bhv = fminf(fmaxf(y2, 0.f), himg) - fminf(fmaxf(y1, 0.f), himg);
        unsigned int valid = (bwv >= 16.f && bhv >= 16.f) ? 1u : 0u;
        out_scores[o] = score;
        boxes_ws[o] = make_float4(x1, y1, x2, y2);
        valid_ws[o] = valid;
    }
}

// -------- Kernel 3: suppression bitmask matrix (rows x 64-col words), 256 thr --------
__global__ __launch_bounds__(256) void k_supmat(const float4* __restrict__ boxes_ws,
                                                unsigned long long* __restrict__ sup) {
    int ct = blockIdx.x;    // col tile 0..31
    int rt = blockIdx.y;    // row super-tile 0..7 (256 rows each)
    int b  = blockIdx.z;
    int tid = threadIdx.x;
    __shared__ float4 colbox[64];
    int j0 = ct * 64;
    if (tid < 64) {
        int jl = j0 + tid;
        colbox[tid] = (jl < KSEL) ? boxes_ws[(size_t)b * KSEL + jl]
                                  : make_float4(0.f, 0.f, 0.f, 0.f);
    }
    __syncthreads();
    int i = rt * 256 + tid;
    if (i >= KSEL) return;
    float4 bi = boxes_ws[(size_t)b * KSEL + i];
    float area_i = (bi.z - bi.x) * (bi.w - bi.y);
    unsigned long long word = 0ULL;
    #pragma unroll 8
    for (int jj = 0; jj < 64; ++jj) {
        int j = j0 + jj;
        float4 bj = colbox[jj];
        float area_j = (bj.z - bj.x) * (bj.w - bj.y);
        float ix1 = fmaxf(bi.x, bj.x);
        float iy1 = fmaxf(bi.y, bj.y);
        float ix2 = fminf(bi.z, bj.z);
        float iy2 = fminf(bi.w, bj.w);
        float iw = fmaxf(ix2 - ix1, 0.f);
        float ih = fmaxf(iy2 - iy1, 0.f);
        float inter = iw * ih;
        float uni = area_i + area_j - inter;
        float iou = inter / fmaxf(uni, 1e-6f);
        bool s = (j > i) && (j < KSEL) && (iou > 0.7f);
        if (s) word |= (1ULL << jj);
    }
    sup[((size_t)b * KSEL + i) * 32 + ct] = word;
}

// -------- Kernel 4: word-tile greedy scan, register tiles + 1-wave chain, 256 thr --------
__global__ __launch_bounds__(256) void k_nms_scan(const unsigned long long* __restrict__ sup,
                                                  const unsigned int* __restrict__ valid_ws,
                                                  const float4* __restrict__ boxes_ws,
                                                  float* __restrict__ out_boxes,
                                                  float* __restrict__ out_keep) {
    int b = blockIdx.x;
    int tid = threadIdx.x;
    int lane = tid & 63;
    int myword = tid & 31;
    __shared__ unsigned long long kws[32];
    __shared__ unsigned long long diag[64];
    __shared__ unsigned long long cur_sh;
    __shared__ unsigned int accw[64];
    const unsigned long long* srow = sup + (size_t)b * KSEL * 32;

    if (tid < 32) {
        unsigned long long kw = 0ULL;
        const uint4* vv = (const uint4*)(valid_ws + (size_t)b * KSEL);
        #pragma unroll 4
        for (int q = 0; q < 16; ++q) {
            uint4 x = vv[tid * 16 + q];   // tid=31,q>=4 reads past 2000 — bits masked below
            int base = q * 4;
            if (x.x) kw |= 1ULL << (base + 0);
            if (x.y) kw |= 1ULL << (base + 1);
            if (x.z) kw |= 1ULL << (base + 2);
            if (x.w) kw |= 1ULL << (base + 3);
        }
        if (tid == 31) kw &= 0xFFFFULL;   // rows 2000..2047 invalid
        kws[tid] = kw;
    }
    if (tid < 64) accw[tid] = 0u;

    // register tile double-buffer: entry e = tid + k*256; row = e>>5, word = e&31 = tid&31
    unsigned long long curv[8], nxt[8];
    #pragma unroll
    for (int k = 0; k < 8; ++k) curv[k] = srow[tid + k * 256];   // tile 0: rows 0..63

    for (int w = 0; w < 32; ++w) {
        // deposit diag column (word w) into LDS: threads with myword==w hold it
        if (myword == w) {
            #pragma unroll
            for (int k = 0; k < 8; ++k) diag[(tid >> 5) + k * 8] = curv[k];
        }
        __syncthreads();   // B1: diag ready; kws/accw from prev iter settled
        // prefetch next tile into regs (latency overlaps chain+apply)
        if (w < 31) {
            int gbase = (w + 1) * 2048;
            #pragma unroll
            for (int k = 0; k < 8; ++k) {
                int e = tid + k * 256;
                int row = (w + 1) * 64 + (e >> 5);
                nxt[k] = (row < KSEL) ? srow[gbase + e] : 0ULL;
            }
        }
        // 64-step greedy chain within word w — wave 0 only (broadcast LDS reads)
        if (tid < 64) {
            unsigned long long cur = kws[w];
            #pragma unroll
            for (int bit = 0; bit < 64; ++bit) {
                unsigned long long msk = 0ULL - ((cur >> bit) & 1ULL);
                cur &= ~(diag[bit] & msk);
            }
            if (tid == 0) cur_sh = cur;
        }
        __syncthreads();   // B2: cur_sh ready
        unsigned long long cur = cur_sh;
        // apply: OR kept rows' sup words straight from registers
        unsigned long long v = 0ULL;
        #pragma unroll
        for (int k = 0; k < 8; ++k) {
            int row = (tid + k * 256) >> 5;
            if ((cur >> row) & 1ULL) v |= curv[k];
        }
        v |= __shfl_xor(v, 32, 64);        // fold row-halves; lanes<32 hold per-word OR
        if (lane < 32 && v) {
            atomicOr(&accw[myword * 2], (unsigned int)v);
            atomicOr(&accw[myword * 2 + 1], (unsigned int)(v >> 32));
        }
        __syncthreads();   // B3: accw complete
        if (tid < 32) {
            unsigned long long a = ((unsigned long long)accw[tid * 2 + 1] << 32)
                                   | (unsigned long long)accw[tid * 2];
            kws[tid] = ((tid == w) ? cur : kws[tid]) & ~a;   // no-op for words <= w
            accw[tid * 2] = 0u;
            accw[tid * 2 + 1] = 0u;
        }
        #pragma unroll
        for (int k = 0; k < 8; ++k) curv[k] = nxt[k];
    }
    __syncthreads();

    for (int r = tid; r < KSEL; r += 256) {
        float kf = (float)((kws[r >> 6] >> (r & 63)) & 1ULL);
        size_t o = (size_t)b * KSEL + r;
        out_keep[o] = kf;
        float4 bx = boxes_ws[o];
        float* ob = out_boxes + o * 4;
        ob[0] = bx.x * kf;
        ob[1] = bx.y * kf;
        ob[2] = bx.z * kf;
        ob[3] = bx.w * kf;
    }
}

extern "C" void kernel_launch(void* const* d_in, const int* in_sizes, int n_in,
                              void* d_out, int out_size, void* d_ws, size_t ws_size,
                              hipStream_t stream) {
    const float* cls     = (const float*)d_in[0];
    const float* regs    = (const float*)d_in[1];
    const float* anchors = (const float*)d_in[2];
    const int*   img_h   = (const int*)d_in[3];
    const int*   img_w   = (const int*)d_in[4];

    float* out = (float*)d_out;
    float* out_boxes  = out;            // 8*2000*4
    float* out_scores = out + 64000;    // 8*2000
    float* out_keep   = out + 80000;    // 8*2000

    char* ws = (char*)d_ws;
    unsigned int* hist1      = (unsigned int*)(ws + OFF_H1);
    unsigned int* ccnt       = (unsigned int*)(ws + OFF_CCNT);
    uint4* selinfo           = (uint4*)(ws + OFF_SEL);
    float4* boxes_ws         = (float4*)(ws + OFF_BOX);
    unsigned int* valid_ws   = (unsigned int*)(ws + OFF_VALID);
    unsigned long long* sup  = (unsigned long long*)(ws + OFF_SUP);
    unsigned long long* cand = (unsigned long long*)(ws + OFF_CAND);

    hipMemsetAsync(ws, 0, ZR_BYTES, stream);
    k_hist1<<<dim3(GSPLIT, NBATCH), 256, 0, stream>>>(cls, hist1);
    k_scan1<<<NBATCH, 1024, 0, stream>>>(hist1, selinfo);
    k_gather<<<dim3(GSPLIT, NBATCH), 256, 0, stream>>>(cls, selinfo, cand, ccnt);
    k_sort_decode<<<NBATCH, 1024, 0, stream>>>(cand, ccnt, selinfo, regs, anchors,
                                               img_h, img_w, out_scores, boxes_ws, valid_ws);
    k_supmat<<<dim3(32, 8, NBATCH), 256, 0, stream>>>(boxes_ws, sup);
    k_nms_scan<<<NBATCH, 256, 0, stream>>>(sup, valid_ws, boxes_ws, out_boxes, out_keep);
}

// Round 6
// 244.867 us; speedup vs baseline: 2.5606x; 1.1414x over previous
//
#include <hip/hip_runtime.h>

// Problem constants (B=8, A=3, H=200, W=304)
#define HWSZ 60800      // H*W
#define NA 3
#define NTOT 182400     // A*H*W
#define KSEL 2000
#define BUFCAP 2048
#define CANDCAP 8192
#define NBATCH 8
#define GSPLIT 128
#define LOG_MAX_F 4.135166556742356f   // log(1000/16) rounded to fp32

// ---- workspace layout (bytes) ----
#define OFF_H1    0          // 8*2048*4 = 65536
#define OFF_CCNT  65536      // 8*4 = 32
#define ZR_BYTES  65568      // zeroes H1 + CCNT
#define OFF_SEL   65568      // 8*16 = 128 (16B aligned)
#define OFF_BOX   65696      // 8*2000*16 = 256000 (16B aligned)
#define OFF_VALID 321696     // 8*2000*4 = 64000
#define OFF_SUP   385696     // 8*2000*32*8 = 4096000 (8B aligned)
#define OFF_CAND  385696     // overlay on sup (disjoint lifetime): 8*8192*8 = 524288

__device__ __forceinline__ unsigned int xform(float f) {
    unsigned int b = __float_as_uint(f);
    return b ^ ((unsigned int)((int)b >> 31) | 0x80000000u);  // monotonic float->uint
}

// ---------------- Kernel A: per-batch 2048-bin hist of top-11 key bits ----------------
__global__ __launch_bounds__(256) void k_hist1(const float* __restrict__ cls,
                                               unsigned int* __restrict__ hist1) {
    int b = blockIdx.y, part = blockIdx.x, tid = threadIdx.x;
    __shared__ unsigned int h[2048];
    for (int i = tid; i < 2048; i += 256) h[i] = 0u;
    __syncthreads();
    const float4* base4 = (const float4*)(cls + (size_t)b * NTOT);
    const int n4 = NTOT / 4;                    // 45600
    int per = (n4 + GSPLIT - 1) / GSPLIT;
    int lo = part * per, hi = lo + per;
    if (hi > n4) hi = n4;
    for (int i = lo + tid; i < hi; i += 256) {
        float4 v = base4[i];
        atomicAdd(&h[xform(v.x) >> 21], 1u);
        atomicAdd(&h[xform(v.y) >> 21], 1u);
        atomicAdd(&h[xform(v.z) >> 21], 1u);
        atomicAdd(&h[xform(v.w) >> 21], 1u);
    }
    __syncthreads();
    unsigned int* gh = hist1 + b * 2048;
    for (int i = tid; i < 2048; i += 256)
        if (h[i]) atomicAdd(&gh[i], h[i]);
}

// ---------------- Kernel B: suffix-scan hist1, find threshold bin ----------------
__global__ __launch_bounds__(1024) void k_scan1(const unsigned int* __restrict__ hist1,
                                                uint4* __restrict__ selinfo) {
    int b = blockIdx.x, tid = threadIdx.x;
    __shared__ unsigned int sa[2048], sb[2048];
    const unsigned int* h = hist1 + b * 2048;
    sa[tid] = h[tid];
    sa[tid + 1024] = h[tid + 1024];
    unsigned int* src = sa; unsigned int* dst = sb;
    for (int d = 1; d < 2048; d <<= 1) {
        __syncthreads();
        dst[tid] = src[tid] + ((tid + d < 2048) ? src[tid + d] : 0u);
        int i2 = tid + 1024;
        dst[i2] = src[i2] + ((i2 + d < 2048) ? src[i2 + d] : 0u);
        unsigned int* t = src; src = dst; dst = t;
    }
    __syncthreads();
    #pragma unroll
    for (int k = 0; k < 2; ++k) {
        int i = tid + k * 1024;
        unsigned int c = src[i];
        unsigned int cn = (i < 2047) ? src[i + 1] : 0u;
        if (c >= KSEL && cn < KSEL)
            selinfo[b] = make_uint4((unsigned int)i, cn, KSEL - cn, 0u);
    }
}

// -------- Kernel C: gather all keys with bin >= threshold bin (block-local compaction) --------
__global__ __launch_bounds__(256) void k_gather(const float* __restrict__ cls,
                                                const uint4* __restrict__ selinfo,
                                                unsigned long long* __restrict__ cand,
                                                unsigned int* __restrict__ ccnt) {
    int b = blockIdx.y, part = blockIdx.x, tid = threadIdx.x;
    unsigned int bin = selinfo[b].x;
    __shared__ unsigned long long lbuf[1024];
    __shared__ unsigned int lcnt, gbase;
    if (tid == 0) lcnt = 0u;
    __syncthreads();
    const float4* base4 = (const float4*)(cls + (size_t)b * NTOT);
    const int n4 = NTOT / 4;
    int per = (n4 + GSPLIT - 1) / GSPLIT;
    int lo = part * per, hi = lo + per;
    if (hi > n4) hi = n4;
    for (int i = lo + tid; i < hi; i += 256) {
        float4 v = base4[i];
        float vals[4] = {v.x, v.y, v.z, v.w};
        int idx0 = i * 4;
        #pragma unroll
        for (int q = 0; q < 4; ++q) {
            unsigned int u = xform(vals[q]);
            if ((u >> 21) >= bin) {
                int idx = idx0 + q;
                int a = idx / HWSZ;
                int hw = idx - a * HWSZ;
                unsigned int n = (unsigned int)(hw * NA + a);
                unsigned int pos = atomicAdd(&lcnt, 1u);
                if (pos < 1024u)
                    lbuf[pos] = ((unsigned long long)u << 32) | (unsigned long long)(~n);
            }
        }
    }
    __syncthreads();
    if (tid == 0) {
        unsigned int c = lcnt < 1024u ? lcnt : 1024u;
        gbase = atomicAdd(&ccnt[b], c);
    }
    __syncthreads();
    unsigned int c = lcnt < 1024u ? lcnt : 1024u;
    unsigned int gb = gbase;
    for (unsigned int i = tid; i < c; i += 256) {
        unsigned int p = gb + i;
        if (p < CANDCAP) cand[(size_t)b * CANDCAP + p] = lbuf[i];
    }
}

// -------- Kernel D: refine threshold + compact + bitonic sort (desc) + box decode --------
__global__ __launch_bounds__(1024) void k_sort_decode(
        const unsigned long long* __restrict__ cand,
        const unsigned int* __restrict__ ccnt,
        const uint4* __restrict__ selinfo,
        const float* __restrict__ regs,
        const float* __restrict__ anchors,
        const int* __restrict__ img_h,
        const int* __restrict__ img_w,
        float* __restrict__ out_scores,
        float4* __restrict__ boxes_ws,
        unsigned int* __restrict__ valid_ws) {
    int b = blockIdx.x;
    int tid = threadIdx.x;
    __shared__ unsigned long long arr[BUFCAP];
    __shared__ unsigned int sa[2048], sb[2048];
    __shared__ unsigned int acnt, shT;
    uint4 si = selinfo[b];
    unsigned int bin = si.x, krem = si.z;
    unsigned int m = ccnt[b];
    if (m > CANDCAP) m = CANDCAP;
    const unsigned long long* cb = cand + (size_t)b * CANDCAP;

    // sub-bin histogram (bits [20:10]) of in-bin candidates
    sa[tid] = 0u; sa[tid + 1024] = 0u;
    if (tid == 0) acnt = 0u;
    __syncthreads();
    for (unsigned int i = tid; i < m; i += 1024) {
        unsigned int u = (unsigned int)(cb[i] >> 32);
        if ((u >> 21) == bin) atomicAdd(&sa[(u >> 10) & 2047u], 1u);
    }
    // suffix scan
    unsigned int* src = sa; unsigned int* dst = sb;
    for (int d = 1; d < 2048; d <<= 1) {
        __syncthreads();
        dst[tid] = src[tid] + ((tid + d < 2048) ? src[tid + d] : 0u);
        int i2 = tid + 1024;
        dst[i2] = src[i2] + ((i2 + d < 2048) ? src[i2 + d] : 0u);
        unsigned int* t = src; src = dst; dst = t;
    }
    __syncthreads();
    #pragma unroll
    for (int k = 0; k < 2; ++k) {
        int i = tid + k * 1024;
        unsigned int c = src[i];
        unsigned int cn = (i < 2047) ? src[i + 1] : 0u;
        if (c >= krem && cn < krem)
            shT = (bin << 21) | ((unsigned int)i << 10);
    }
    __syncthreads();
    unsigned int T = shT;

    // compact keys >= T into arr via wave-ballot (+1 LDS atomic per wave-iter)
    int lane = tid & 63;
    unsigned long long lmask = (1ULL << lane) - 1ULL;
    unsigned int mr = (m + 1023u) & ~1023u;
    for (unsigned int i = tid; i < mr; i += 1024) {
        bool pred = false;
        unsigned long long key = 0ULL;
        if (i < m) {
            key = cb[i];
            pred = ((unsigned int)(key >> 32)) >= T;
        }
        unsigned long long mask = __ballot(pred);
        unsigned int cw = (unsigned int)__popcll(mask);
        unsigned int base = 0u;
        if (lane == 0 && cw) base = atomicAdd(&acnt, cw);
        base = __shfl(base, 0, 64);
        if (pred) {
            unsigned int pos = base + (unsigned int)__popcll(mask & lmask);
            if (pos < BUFCAP) arr[pos] = key;
        }
    }
    __syncthreads();
    unsigned int total = acnt < BUFCAP ? acnt : BUFCAP;
    for (unsigned int i = tid; i < BUFCAP; i += 1024)
        if (i >= total) arr[i] = 0ULL;
    __syncthreads();

    // bitonic sort, descending by packed key
    for (int k = 2; k <= BUFCAP; k <<= 1) {
        for (int j = k >> 1; j > 0; j >>= 1) {
            for (int i = tid; i < BUFCAP; i += 1024) {
                int ixj = i ^ j;
                if (ixj > i) {
                    unsigned long long x = arr[i], y = arr[ixj];
                    bool up = (i & k) == 0;
                    if (up ? (x < y) : (x > y)) { arr[i] = y; arr[ixj] = x; }
                }
            }
            __syncthreads();
        }
    }

    int hv = img_h[0];
    int wv = img_w[0];
    float himg = (hv > 0 && hv < 100000) ? (float)hv : __int_as_float(hv);
    float wimg = (wv > 0 && wv < 100000) ? (float)wv : __int_as_float(wv);

    for (int r = tid; r < KSEL; r += 1024) {
        unsigned long long packed = arr[r];
        size_t o = (size_t)b * KSEL + r;
        if (packed == 0ULL) {
            out_scores[o] = 0.f;
            boxes_ws[o] = make_float4(0.f, 0.f, 0.f, 0.f);
            valid_ws[o] = 0u;
            continue;
        }
        unsigned int u = (unsigned int)(packed >> 32);
        unsigned int n = ~((unsigned int)packed);
        unsigned int bits = (u & 0x80000000u) ? (u & 0x7FFFFFFFu) : ~u;
        float score = __uint_as_float(bits);
        int a = (int)(n % NA);
        int hw = (int)(n / NA);
        const float* rp = regs + ((size_t)b * (4 * NA) + 4 * a) * HWSZ + hw;
        float dx = rp[0 * HWSZ];
        float dy = rp[1 * HWSZ];
        float dh = rp[2 * HWSZ];
        float dw = rp[3 * HWSZ];
        const float* ap = anchors + ((size_t)b * NTOT + n) * 4;
        float ax1 = ap[0], ay1 = ap[1], ax2 = ap[2], ay2 = ap[3];
        float ahh = ay2 - ay1;
        float aww = ax2 - ax1;
        float cx = aww * 0.5f;
        float cy = ahh * 0.5f;
        float px = cx + dx * aww;
        float py = cy + dy * ahh;
        dh = fminf(dh, LOG_MAX_F);
        dw = fminf(dw, LOG_MAX_F);
        float ph = expf(dh) * ahh;
        float pw = expf(dw) * aww;
        float x1 = px - pw * 0.5f;
        float y1 = py - ph * 0.5f;
        float x2 = px + pw * 0.5f;
        float y2 = py + ph * 0.5f;
        float bwv = fminf(fmaxf(x2, 0.f), wimg) - fminf(fmaxf(x1, 0.f), wimg);
        float bhv = fminf(fmaxf(y2, 0.f), himg) - fminf(fmaxf(y1, 0.f), himg);
        unsigned int valid = (bwv >= 16.f && bhv >= 16.f) ? 1u : 0u;
        out_scores[o] = score;
        boxes_ws[o] = make_float4(x1, y1, x2, y2);
        valid_ws[o] = valid;
    }
}

// -------- Kernel 3: suppression bitmask matrix (rows x 64-col words), 256 thr --------
__global__ __launch_bounds__(256) void k_supmat(const float4* __restrict__ boxes_ws,
                                                unsigned long long* __restrict__ sup) {
    int ct = blockIdx.x;    // col tile 0..31
    int rt = blockIdx.y;    // row super-tile 0..7 (256 rows each)
    int b  = blockIdx.z;
    int tid = threadIdx.x;
    __shared__ float4 colbox[64];
    int j0 = ct * 64;
    if (tid < 64) {
        int jl = j0 + tid;
        colbox[tid] = (jl < KSEL) ? boxes_ws[(size_t)b * KSEL + jl]
                                  : make_float4(0.f, 0.f, 0.f, 0.f);
    }
    __syncthreads();
    int i = rt * 256 + tid;
    if (i >= KSEL) return;
    float4 bi = boxes_ws[(size_t)b * KSEL + i];
    float area_i = (bi.z - bi.x) * (bi.w - bi.y);
    unsigned long long word = 0ULL;
    #pragma unroll 8
    for (int jj = 0; jj < 64; ++jj) {
        int j = j0 + jj;
        float4 bj = colbox[jj];
        float area_j = (bj.z - bj.x) * (bj.w - bj.y);
        float ix1 = fmaxf(bi.x, bj.x);
        float iy1 = fmaxf(bi.y, bj.y);
        float ix2 = fminf(bi.z, bj.z);
        float iy2 = fminf(bi.w, bj.w);
        float iw = fmaxf(ix2 - ix1, 0.f);
        float ih = fmaxf(iy2 - iy1, 0.f);
        float inter = iw * ih;
        float uni = area_i + area_j - inter;
        float iou = inter / fmaxf(uni, 1e-6f);
        bool s = (j > i) && (j < KSEL) && (iou > 0.7f);
        if (s) word |= (1ULL << jj);
    }
    sup[((size_t)b * KSEL + i) * 32 + ct] = word;
}

// -------- Kernel 4: word-tile greedy scan — scalar chain, lazy accw, 1 barrier/iter --------
__global__ __launch_bounds__(256) void k_nms_scan(const unsigned long long* __restrict__ sup,
                                                  const unsigned int* __restrict__ valid_ws,
                                                  const float4* __restrict__ boxes_ws,
                                                  float* __restrict__ out_boxes,
                                                  float* __restrict__ out_keep) {
    int b = blockIdx.x;
    int tid = threadIdx.x;
    int lane = tid & 63;
    int myword = tid & 31;
    __shared__ unsigned long long kws[32];     // initial validity words (read-only in loop)
    __shared__ unsigned long long fin[32];     // final keep words
    __shared__ unsigned long long diag[64];    // current tile's word-w column
    __shared__ unsigned int accw[64];          // lazy suppression accumulator (monotone)
    const unsigned long long* srow = sup + (size_t)b * KSEL * 32;

    if (tid < 32) {
        unsigned long long kw = 0ULL;
        const uint4* vv = (const uint4*)(valid_ws + (size_t)b * KSEL);
        #pragma unroll 4
        for (int q = 0; q < 16; ++q) {
            uint4 x = vv[tid * 16 + q];   // tid=31,q>=4 reads past 2000 — bits masked below
            int base = q * 4;
            if (x.x) kw |= 1ULL << (base + 0);
            if (x.y) kw |= 1ULL << (base + 1);
            if (x.z) kw |= 1ULL << (base + 2);
            if (x.w) kw |= 1ULL << (base + 3);
        }
        if (tid == 31) kw &= 0xFFFFULL;   // rows 2000..2047 invalid
        kws[tid] = kw;
    }
    if (tid < 64) accw[tid] = 0u;

    // register tile double-buffer: entry e = tid + k*256; row = e>>5, word = e&31 = tid&31
    unsigned long long curv[8], nxt[8];
    #pragma unroll
    for (int k = 0; k < 8; ++k) curv[k] = srow[tid + k * 256];   // tile 0: rows 0..63

    for (int w = 0; w < 32; ++w) {
        // deposit diag column (word w) into LDS: threads with myword==w hold it
        if (myword == w) {
            #pragma unroll
            for (int k = 0; k < 8; ++k) diag[(tid >> 5) + k * 8] = curv[k];
        }
        __syncthreads();   // B1: diag ready; all prior applies visible in accw

        // prefetch next tile into regs (latency overlaps chain+apply)
        if (w < 31) {
            int gbase = (w + 1) * 2048;
            #pragma unroll
            for (int k = 0; k < 8; ++k) {
                int e = tid + k * 256;
                int row = (w + 1) * 64 + (e >> 5);
                nxt[k] = (row < KSEL) ? srow[gbase + e] : 0ULL;
            }
        }

        // per-wave redundant scalar chain: lane l holds diag row l
        unsigned long long dval = diag[lane];
        unsigned int dlo = (unsigned int)dval;
        unsigned int dhi = (unsigned int)(dval >> 32);
        unsigned long long k0 = kws[w];
        unsigned long long pend = ((unsigned long long)accw[w * 2 + 1] << 32)
                                  | (unsigned long long)accw[w * 2];
        unsigned long long c64 = k0 & ~pend;
        unsigned int clo = __builtin_amdgcn_readfirstlane((unsigned int)c64);
        unsigned int chi = __builtin_amdgcn_readfirstlane((unsigned int)(c64 >> 32));
        unsigned long long cur = ((unsigned long long)chi << 32) | (unsigned long long)clo;
        #pragma unroll
        for (int bit = 0; bit < 64; ++bit) {
            if ((cur >> bit) & 1ULL) {
                unsigned int lo = (unsigned int)__builtin_amdgcn_readlane((int)dlo, bit);
                unsigned int hi = (unsigned int)__builtin_amdgcn_readlane((int)dhi, bit);
                cur &= ~(((unsigned long long)hi << 32) | (unsigned long long)lo);
            }
        }
        if (tid == 0) fin[w] = cur;

        // apply: OR kept rows' sup words straight from registers into lazy accw
        unsigned long long v = 0ULL;
        #pragma unroll
        for (int k = 0; k < 8; ++k) {
            int row = (tid + k * 256) >> 5;
            if ((cur >> row) & 1ULL) v |= curv[k];
        }
        v |= __shfl_xor(v, 32, 64);        // fold row-halves; lanes<32 hold per-word OR
        if (lane < 32 && v) {
            atomicOr(&accw[myword * 2], (unsigned int)v);
            atomicOr(&accw[myword * 2 + 1], (unsigned int)(v >> 32));
        }
        // no trailing barrier: next iteration's B1 makes accw/fin visible

        #pragma unroll
        for (int k = 0; k < 8; ++k) curv[k] = nxt[k];
    }
    __syncthreads();

    for (int r = tid; r < KSEL; r += 256) {
        float kf = (float)((fin[r >> 6] >> (r & 63)) & 1ULL);
        size_t o = (size_t)b * KSEL + r;
        out_keep[o] = kf;
        float4 bx = boxes_ws[o];
        float* ob = out_boxes + o * 4;
        ob[0] = bx.x * kf;
        ob[1] = bx.y * kf;
        ob[2] = bx.z * kf;
        ob[3] = bx.w * kf;
    }
}

extern "C" void kernel_launch(void* const* d_in, const int* in_sizes, int n_in,
                              void* d_out, int out_size, void* d_ws, size_t ws_size,
                              hipStream_t stream) {
    const float* cls     = (const float*)d_in[0];
    const float* regs    = (const float*)d_in[1];
    const float* anchors = (const float*)d_in[2];
    const int*   img_h   = (const int*)d_in[3];
    const int*   img_w   = (const int*)d_in[4];

    float* out = (float*)d_out;
    float* out_boxes  = out;            // 8*2000*4
    float* out_scores = out + 64000;    // 8*2000
    float* out_keep   = out + 80000;    // 8*2000

    char* ws = (char*)d_ws;
    unsigned int* hist1      = (unsigned int*)(ws + OFF_H1);
    unsigned int* ccnt       = (unsigned int*)(ws + OFF_CCNT);
    uint4* selinfo           = (uint4*)(ws + OFF_SEL);
    float4* boxes_ws         = (float4*)(ws + OFF_BOX);
    unsigned int* valid_ws   = (unsigned int*)(ws + OFF_VALID);
    unsigned long long* sup  = (unsigned long long*)(ws + OFF_SUP);
    unsigned long long* cand = (unsigned long long*)(ws + OFF_CAND);

    hipMemsetAsync(ws, 0, ZR_BYTES, stream);
    k_hist1<<<dim3(GSPLIT, NBATCH), 256, 0, stream>>>(cls, hist1);
    k_scan1<<<NBATCH, 1024, 0, stream>>>(hist1, selinfo);
    k_gather<<<dim3(GSPLIT, NBATCH), 256, 0, stream>>>(cls, selinfo, cand, ccnt);
    k_sort_decode<<<NBATCH, 1024, 0, stream>>>(cand, ccnt, selinfo, regs, anchors,
                                               img_h, img_w, out_scores, boxes_ws, valid_ws);
    k_supmat<<<dim3(32, 8, NBATCH), 256, 0, stream>>>(boxes_ws, sup);
    k_nms_scan<<<NBATCH, 256, 0, stream>>>(sup, valid_ws, boxes_ws, out_boxes, out_keep);
}

// Round 7
// 231.863 us; speedup vs baseline: 2.7042x; 1.0561x over previous
//
#include <hip/hip_runtime.h>

// Problem constants (B=8, A=3, H=200, W=304)
#define HWSZ 60800      // H*W
#define NA 3
#define NTOT 182400     // A*H*W
#define KSEL 2000
#define CANDCAP 8192
#define SELCAP 4096
#define NBATCH 8
#define GSPLIT 128
#define LOG_MAX_F 4.135166556742356f   // log(1000/16) rounded to fp32

// ---- workspace layout (bytes) ----
#define OFF_H1    0          // 8*2048*4 = 65536
#define OFF_CCNT  65536      // 8*4 = 32
#define OFF_SCNT  65568      // 8*4 = 32
#define ZR_BYTES  65600      // zeroes H1 + CCNT + SCNT
#define OFF_SEL   65600      // 8*16 = 128 (16B aligned)
#define OFF_BOX   65728      // 8*2000*16 = 256000 (16B aligned)
#define OFF_VALID 321728     // 8*2000*4 = 64000
#define OFF_SUP   385728     // 8*2000*32*8 = 4096000 (8B aligned)
#define OFF_CAND  385728     // overlay on sup (lifetime: gather->refine): 8*8192*8 = 524288
#define OFF_SELK  910016     // overlay on sup (lifetime: refine->rank): 8*4096*8 = 262144

__device__ __forceinline__ unsigned int xform(float f) {
    unsigned int b = __float_as_uint(f);
    return b ^ ((unsigned int)((int)b >> 31) | 0x80000000u);  // monotonic float->uint
}

// ---------------- Kernel A: per-batch 2048-bin hist of top-11 key bits ----------------
__global__ __launch_bounds__(256) void k_hist1(const float* __restrict__ cls,
                                               unsigned int* __restrict__ hist1) {
    int b = blockIdx.y, part = blockIdx.x, tid = threadIdx.x;
    __shared__ unsigned int h[2048];
    for (int i = tid; i < 2048; i += 256) h[i] = 0u;
    __syncthreads();
    const float4* base4 = (const float4*)(cls + (size_t)b * NTOT);
    const int n4 = NTOT / 4;
    int per = (n4 + GSPLIT - 1) / GSPLIT;
    int lo = part * per, hi = lo + per;
    if (hi > n4) hi = n4;
    for (int i = lo + tid; i < hi; i += 256) {
        float4 v = base4[i];
        atomicAdd(&h[xform(v.x) >> 21], 1u);
        atomicAdd(&h[xform(v.y) >> 21], 1u);
        atomicAdd(&h[xform(v.z) >> 21], 1u);
        atomicAdd(&h[xform(v.w) >> 21], 1u);
    }
    __syncthreads();
    unsigned int* gh = hist1 + b * 2048;
    for (int i = tid; i < 2048; i += 256)
        if (h[i]) atomicAdd(&gh[i], h[i]);
}

// ---------------- Kernel B: suffix-scan hist1, find threshold bin ----------------
__global__ __launch_bounds__(1024) void k_scan1(const unsigned int* __restrict__ hist1,
                                                uint4* __restrict__ selinfo) {
    int b = blockIdx.x, tid = threadIdx.x;
    __shared__ unsigned int sa[2048], sb[2048];
    const unsigned int* h = hist1 + b * 2048;
    sa[tid] = h[tid];
    sa[tid + 1024] = h[tid + 1024];
    unsigned int* src = sa; unsigned int* dst = sb;
    for (int d = 1; d < 2048; d <<= 1) {
        __syncthreads();
        dst[tid] = src[tid] + ((tid + d < 2048) ? src[tid + d] : 0u);
        int i2 = tid + 1024;
        dst[i2] = src[i2] + ((i2 + d < 2048) ? src[i2 + d] : 0u);
        unsigned int* t = src; src = dst; dst = t;
    }
    __syncthreads();
    #pragma unroll
    for (int k = 0; k < 2; ++k) {
        int i = tid + k * 1024;
        unsigned int c = src[i];
        unsigned int cn = (i < 2047) ? src[i + 1] : 0u;
        if (c >= KSEL && cn < KSEL)
            selinfo[b] = make_uint4((unsigned int)i, cn, KSEL - cn, 0u);
    }
}

// -------- Kernel C: gather all keys with bin >= threshold bin (block-local compaction) --------
__global__ __launch_bounds__(256) void k_gather(const float* __restrict__ cls,
                                                const uint4* __restrict__ selinfo,
                                                unsigned long long* __restrict__ cand,
                                                unsigned int* __restrict__ ccnt) {
    int b = blockIdx.y, part = blockIdx.x, tid = threadIdx.x;
    unsigned int bin = selinfo[b].x;
    __shared__ unsigned long long lbuf[1024];
    __shared__ unsigned int lcnt, gbase;
    if (tid == 0) lcnt = 0u;
    __syncthreads();
    const float4* base4 = (const float4*)(cls + (size_t)b * NTOT);
    const int n4 = NTOT / 4;
    int per = (n4 + GSPLIT - 1) / GSPLIT;
    int lo = part * per, hi = lo + per;
    if (hi > n4) hi = n4;
    for (int i = lo + tid; i < hi; i += 256) {
        float4 v = base4[i];
        float vals[4] = {v.x, v.y, v.z, v.w};
        int idx0 = i * 4;
        #pragma unroll
        for (int q = 0; q < 4; ++q) {
            unsigned int u = xform(vals[q]);
            if ((u >> 21) >= bin) {
                int idx = idx0 + q;
                int a = idx / HWSZ;
                int hw = idx - a * HWSZ;
                unsigned int n = (unsigned int)(hw * NA + a);
                unsigned int pos = atomicAdd(&lcnt, 1u);
                if (pos < 1024u)
                    lbuf[pos] = ((unsigned long long)u << 32) | (unsigned long long)(~n);
            }
        }
    }
    __syncthreads();
    if (tid == 0) {
        unsigned int c = lcnt < 1024u ? lcnt : 1024u;
        gbase = atomicAdd(&ccnt[b], c);
    }
    __syncthreads();
    unsigned int c = lcnt < 1024u ? lcnt : 1024u;
    unsigned int gb = gbase;
    for (unsigned int i = tid; i < c; i += 256) {
        unsigned int p = gb + i;
        if (p < CANDCAP) cand[(size_t)b * CANDCAP + p] = lbuf[i];
    }
}

// -------- Kernel D: refine exact threshold + compact selected keys (no sort) --------
__global__ __launch_bounds__(1024) void k_refine(const unsigned long long* __restrict__ cand,
                                                 const unsigned int* __restrict__ ccnt,
                                                 const uint4* __restrict__ selinfo,
                                                 unsigned long long* __restrict__ selk,
                                                 unsigned int* __restrict__ scnt) {
    int b = blockIdx.x;
    int tid = threadIdx.x;
    __shared__ unsigned int sa[2048], sb[2048];
    __shared__ unsigned int acnt, shT;
    uint4 si = selinfo[b];
    unsigned int bin = si.x, krem = si.z;
    unsigned int m = ccnt[b];
    if (m > CANDCAP) m = CANDCAP;
    const unsigned long long* cb = cand + (size_t)b * CANDCAP;

    // sub-bin histogram (bits [20:10]) of in-bin candidates
    sa[tid] = 0u; sa[tid + 1024] = 0u;
    if (tid == 0) acnt = 0u;
    __syncthreads();
    for (unsigned int i = tid; i < m; i += 1024) {
        unsigned int u = (unsigned int)(cb[i] >> 32);
        if ((u >> 21) == bin) atomicAdd(&sa[(u >> 10) & 2047u], 1u);
    }
    // suffix scan
    unsigned int* src = sa; unsigned int* dst = sb;
    for (int d = 1; d < 2048; d <<= 1) {
        __syncthreads();
        dst[tid] = src[tid] + ((tid + d < 2048) ? src[tid + d] : 0u);
        int i2 = tid + 1024;
        dst[i2] = src[i2] + ((i2 + d < 2048) ? src[i2 + d] : 0u);
        unsigned int* t = src; src = dst; dst = t;
    }
    __syncthreads();
    #pragma unroll
    for (int k = 0; k < 2; ++k) {
        int i = tid + k * 1024;
        unsigned int c = src[i];
        unsigned int cn = (i < 2047) ? src[i + 1] : 0u;
        if (c >= krem && cn < krem)
            shT = (bin << 21) | ((unsigned int)i << 10);
    }
    __syncthreads();
    unsigned int T = shT;

    // compact keys >= T into selk via wave-ballot (order irrelevant — rank fixes it)
    int lane = tid & 63;
    unsigned long long lmask = (1ULL << lane) - 1ULL;
    unsigned int mr = (m + 1023u) & ~1023u;
    unsigned long long* sout = selk + (size_t)b * SELCAP;
    for (unsigned int i = tid; i < mr; i += 1024) {
        bool pred = false;
        unsigned long long key = 0ULL;
        if (i < m) {
            key = cb[i];
            pred = ((unsigned int)(key >> 32)) >= T;
        }
        unsigned long long mask = __ballot(pred);
        unsigned int cw = (unsigned int)__popcll(mask);
        unsigned int base = 0u;
        if (lane == 0 && cw) base = atomicAdd(&acnt, cw);
        base = __shfl(base, 0, 64);
        if (pred) {
            unsigned int pos = base + (unsigned int)__popcll(mask & lmask);
            if (pos < SELCAP) sout[pos] = key;
        }
    }
    __syncthreads();
    if (tid == 0) scnt[b] = (acnt < SELCAP) ? acnt : SELCAP;
}

// -------- Kernel E: rank-by-count + box decode, writes at out position = rank --------
__global__ __launch_bounds__(256) void k_rank_decode(
        const unsigned long long* __restrict__ selk,
        const unsigned int* __restrict__ scnt,
        const float* __restrict__ regs,
        const float* __restrict__ anchors,
        const int* __restrict__ img_h,
        const int* __restrict__ img_w,
        float* __restrict__ out_scores,
        float4* __restrict__ boxes_ws,
        unsigned int* __restrict__ valid_ws) {
    int b = blockIdx.y;
    int tid = threadIdx.x;
    int lane = tid & 63;
    unsigned int sc = scnt[b];
    if (sc > SELCAP) sc = SELCAP;
    unsigned int r = blockIdx.x * 256 + tid;
    if (blockIdx.x * 256 >= sc) return;   // uniform early-out for spare blocks
    const unsigned long long* sb_ = selk + (size_t)b * SELCAP;
    unsigned long long mykey = (r < sc) ? sb_[r] : 0ULL;

    // rank = #{selected keys > mykey}; stream columns 64 at a time, broadcast via readlane
    unsigned int cnt = 0u;
    for (unsigned int base = 0; base < sc; base += 64) {
        unsigned long long kj = 0ULL;
        if (base + (unsigned int)lane < sc) kj = sb_[base + lane];
        unsigned int klo = (unsigned int)kj;
        unsigned int khi = (unsigned int)(kj >> 32);
        #pragma unroll
        for (int t = 0; t < 64; ++t) {
            unsigned int lo = (unsigned int)__builtin_amdgcn_readlane((int)klo, t);
            unsigned int hi = (unsigned int)__builtin_amdgcn_readlane((int)khi, t);
            unsigned long long kt = ((unsigned long long)hi << 32) | (unsigned long long)lo;
            cnt += (kt > mykey) ? 1u : 0u;
        }
    }
    if (r >= sc || cnt >= KSEL) return;

    int hv = img_h[0];
    int wv = img_w[0];
    float himg = (hv > 0 && hv < 100000) ? (float)hv : __int_as_float(hv);
    float wimg = (wv > 0 && wv < 100000) ? (float)wv : __int_as_float(wv);

    unsigned int u = (unsigned int)(mykey >> 32);
    unsigned int n = ~((unsigned int)mykey);
    unsigned int bits = (u & 0x80000000u) ? (u & 0x7FFFFFFFu) : ~u;
    float score = __uint_as_float(bits);
    int a = (int)(n % NA);
    int hw = (int)(n / NA);
    const float* rp = regs + ((size_t)b * (4 * NA) + 4 * a) * HWSZ + hw;
    float dx = rp[0 * HWSZ];
    float dy = rp[1 * HWSZ];
    float dh = rp[2 * HWSZ];
    float dw = rp[3 * HWSZ];
    const float* ap = anchors + ((size_t)b * NTOT + n) * 4;
    float ax1 = ap[0], ay1 = ap[1], ax2 = ap[2], ay2 = ap[3];
    float ahh = ay2 - ay1;
    float aww = ax2 - ax1;
    float cx = aww * 0.5f;
    float cy = ahh * 0.5f;
    float px = cx + dx * aww;
    float py = cy + dy * ahh;
    dh = fminf(dh, LOG_MAX_F);
    dw = fminf(dw, LOG_MAX_F);
    float ph = expf(dh) * ahh;
    float pw = expf(dw) * aww;
    float x1 = px - pw * 0.5f;
    float y1 = py - ph * 0.5f;
    float x2 = px + pw * 0.5f;
    float y2 = py + ph * 0.5f;
    float bwv = fminf(fmaxf(x2, 0.f), wimg) - fminf(fmaxf(x1, 0.f), wimg);
    float bhv = fminf(fmaxf(y2, 0.f), himg) - fminf(fmaxf(y1, 0.f), himg);
    unsigned int valid = (bwv >= 16.f && bhv >= 16.f) ? 1u : 0u;
    size_t o = (size_t)b * KSEL + cnt;   // output position = rank
    out_scores[o] = score;
    boxes_ws[o] = make_float4(x1, y1, x2, y2);
    valid_ws[o] = valid;
}

// -------- Kernel 3: suppression bitmask matrix (rows x 64-col words), 256 thr --------
__global__ __launch_bounds__(256) void k_supmat(const float4* __restrict__ boxes_ws,
                                                unsigned long long* __restrict__ sup) {
    int ct = blockIdx.x;    // col tile 0..31
    int rt = blockIdx.y;    // row super-tile 0..7 (256 rows each)
    int b  = blockIdx.z;
    int tid = threadIdx.x;
    __shared__ float4 colbox[64];
    int j0 = ct * 64;
    if (tid < 64) {
        int jl = j0 + tid;
        colbox[tid] = (jl < KSEL) ? boxes_ws[(size_t)b * KSEL + jl]
                                  : make_float4(0.f, 0.f, 0.f, 0.f);
    }
    __syncthreads();
    int i = rt * 256 + tid;
    if (i >= KSEL) return;
    float4 bi = boxes_ws[(size_t)b * KSEL + i];
    float area_i = (bi.z - bi.x) * (bi.w - bi.y);
    unsigned long long word = 0ULL;
    #pragma unroll 8
    for (int jj = 0; jj < 64; ++jj) {
        int j = j0 + jj;
        float4 bj = colbox[jj];
        float area_j = (bj.z - bj.x) * (bj.w - bj.y);
        float ix1 = fmaxf(bi.x, bj.x);
        float iy1 = fmaxf(bi.y, bj.y);
        float ix2 = fminf(bi.z, bj.z);
        float iy2 = fminf(bi.w, bj.w);
        float iw = fmaxf(ix2 - ix1, 0.f);
        float ih = fmaxf(iy2 - iy1, 0.f);
        float inter = iw * ih;
        float uni = area_i + area_j - inter;
        float iou = inter / fmaxf(uni, 1e-6f);
        bool s = (j > i) && (j < KSEL) && (iou > 0.7f);
        if (s) word |= (1ULL << jj);
    }
    sup[((size_t)b * KSEL + i) * 32 + ct] = word;
}

// -------- Kernel 4: word-tile greedy scan — scalar chain, lazy accw, 1 barrier/iter --------
__global__ __launch_bounds__(256) void k_nms_scan(const unsigned long long* __restrict__ sup,
                                                  const unsigned int* __restrict__ valid_ws,
                                                  const float4* __restrict__ boxes_ws,
                                                  float* __restrict__ out_boxes,
                                                  float* __restrict__ out_keep) {
    int b = blockIdx.x;
    int tid = threadIdx.x;
    int lane = tid & 63;
    int myword = tid & 31;
    __shared__ unsigned long long kws[32];     // initial validity words (read-only in loop)
    __shared__ unsigned long long fin[32];     // final keep words
    __shared__ unsigned long long diag[64];    // current tile's word-w column
    __shared__ unsigned int accw[64];          // lazy suppression accumulator (monotone)
    const unsigned long long* srow = sup + (size_t)b * KSEL * 32;

    if (tid < 32) {
        unsigned long long kw = 0ULL;
        const uint4* vv = (const uint4*)(valid_ws + (size_t)b * KSEL);
        #pragma unroll 4
        for (int q = 0; q < 16; ++q) {
            uint4 x = vv[tid * 16 + q];   // tid=31,q>=4 reads past 2000 — bits masked below
            int base = q * 4;
            if (x.x) kw |= 1ULL << (base + 0);
            if (x.y) kw |= 1ULL << (base + 1);
            if (x.z) kw |= 1ULL << (base + 2);
            if (x.w) kw |= 1ULL << (base + 3);
        }
        if (tid == 31) kw &= 0xFFFFULL;   // rows 2000..2047 invalid
        kws[tid] = kw;
    }
    if (tid < 64) accw[tid] = 0u;

    // register tile double-buffer: entry e = tid + k*256; row = e>>5, word = e&31 = tid&31
    unsigned long long curv[8], nxt[8];
    #pragma unroll
    for (int k = 0; k < 8; ++k) curv[k] = srow[tid + k * 256];   // tile 0: rows 0..63

    for (int w = 0; w < 32; ++w) {
        if (myword == w) {
            #pragma unroll
            for (int k = 0; k < 8; ++k) diag[(tid >> 5) + k * 8] = curv[k];
        }
        __syncthreads();   // B1: diag ready; all prior applies visible in accw

        if (w < 31) {
            int gbase = (w + 1) * 2048;
            #pragma unroll
            for (int k = 0; k < 8; ++k) {
                int e = tid + k * 256;
                int row = (w + 1) * 64 + (e >> 5);
                nxt[k] = (row < KSEL) ? srow[gbase + e] : 0ULL;
            }
        }

        // per-wave redundant scalar chain: lane l holds diag row l
        unsigned long long dval = diag[lane];
        unsigned int dlo = (unsigned int)dval;
        unsigned int dhi = (unsigned int)(dval >> 32);
        unsigned long long k0 = kws[w];
        unsigned long long pend = ((unsigned long long)accw[w * 2 + 1] << 32)
                                  | (unsigned long long)accw[w * 2];
        unsigned long long c64 = k0 & ~pend;
        unsigned int clo = __builtin_amdgcn_readfirstlane((unsigned int)c64);
        unsigned int chi = __builtin_amdgcn_readfirstlane((unsigned int)(c64 >> 32));
        unsigned long long cur = ((unsigned long long)chi << 32) | (unsigned long long)clo;
        #pragma unroll
        for (int bit = 0; bit < 64; ++bit) {
            if ((cur >> bit) & 1ULL) {
                unsigned int lo = (unsigned int)__builtin_amdgcn_readlane((int)dlo, bit);
                unsigned int hi = (unsigned int)__builtin_amdgcn_readlane((int)dhi, bit);
                cur &= ~(((unsigned long long)hi << 32) | (unsigned long long)lo);
            }
        }
        if (tid == 0) fin[w] = cur;

        // apply: OR kept rows' sup words straight from registers into lazy accw
        unsigned long long v = 0ULL;
        #pragma unroll
        for (int k = 0; k < 8; ++k) {
            int row = (tid + k * 256) >> 5;
            if ((cur >> row) & 1ULL) v |= curv[k];
        }
        v |= __shfl_xor(v, 32, 64);
        if (lane < 32 && v) {
            atomicOr(&accw[myword * 2], (unsigned int)v);
            atomicOr(&accw[myword * 2 + 1], (unsigned int)(v >> 32));
        }

        #pragma unroll
        for (int k = 0; k < 8; ++k) curv[k] = nxt[k];
    }
    __syncthreads();

    for (int r = tid; r < KSEL; r += 256) {
        float kf = (float)((fin[r >> 6] >> (r & 63)) & 1ULL);
        size_t o = (size_t)b * KSEL + r;
        out_keep[o] = kf;
        float4 bx = boxes_ws[o];
        float* ob = out_boxes + o * 4;
        ob[0] = bx.x * kf;
        ob[1] = bx.y * kf;
        ob[2] = bx.z * kf;
        ob[3] = bx.w * kf;
    }
}

extern "C" void kernel_launch(void* const* d_in, const int* in_sizes, int n_in,
                              void* d_out, int out_size, void* d_ws, size_t ws_size,
                              hipStream_t stream) {
    const float* cls     = (const float*)d_in[0];
    const float* regs    = (const float*)d_in[1];
    const float* anchors = (const float*)d_in[2];
    const int*   img_h   = (const int*)d_in[3];
    const int*   img_w   = (const int*)d_in[4];

    float* out = (float*)d_out;
    float* out_boxes  = out;            // 8*2000*4
    float* out_scores = out + 64000;    // 8*2000
    float* out_keep   = out + 80000;    // 8*2000

    char* ws = (char*)d_ws;
    unsigned int* hist1      = (unsigned int*)(ws + OFF_H1);
    unsigned int* ccnt       = (unsigned int*)(ws + OFF_CCNT);
    unsigned int* scnt       = (unsigned int*)(ws + OFF_SCNT);
    uint4* selinfo           = (uint4*)(ws + OFF_SEL);
    float4* boxes_ws         = (float4*)(ws + OFF_BOX);
    unsigned int* valid_ws   = (unsigned int*)(ws + OFF_VALID);
    unsigned long long* sup  = (unsigned long long*)(ws + OFF_SUP);
    unsigned long long* cand = (unsigned long long*)(ws + OFF_CAND);
    unsigned long long* selk = (unsigned long long*)(ws + OFF_SELK);

    hipMemsetAsync(ws, 0, ZR_BYTES, stream);
    k_hist1<<<dim3(GSPLIT, NBATCH), 256, 0, stream>>>(cls, hist1);
    k_scan1<<<NBATCH, 1024, 0, stream>>>(hist1, selinfo);
    k_gather<<<dim3(GSPLIT, NBATCH), 256, 0, stream>>>(cls, selinfo, cand, ccnt);
    k_refine<<<NBATCH, 1024, 0, stream>>>(cand, ccnt, selinfo, selk, scnt);
    k_rank_decode<<<dim3(10, NBATCH), 256, 0, stream>>>(selk, scnt, regs, anchors,
                                                        img_h, img_w, out_scores,
                                                        boxes_ws, valid_ws);
    k_supmat<<<dim3(32, 8, NBATCH), 256, 0, stream>>>(boxes_ws, sup);
    k_nms_scan<<<NBATCH, 256, 0, stream>>>(sup, valid_ws, boxes_ws, out_boxes, out_keep);
}

// Round 8
// 220.272 us; speedup vs baseline: 2.8465x; 1.0526x over previous
//
#include <hip/hip_runtime.h>

// Problem constants (B=8, A=3, H=200, W=304)
#define HWSZ 60800      // H*W
#define NA 3
#define NTOT 182400     // A*H*W
#define KSEL 2000
#define CANDCAP 8192
#define SELCAP 4096
#define NBATCH 8
#define GSPLIT 128
#define LOG_MAX_F 4.135166556742356f   // log(1000/16) rounded to fp32

// ---- workspace layout (bytes) ----
#define OFF_H1    0          // 8*2048*4 = 65536
#define OFF_CCNT  65536      // 8*4 = 32
#define OFF_SCNT  65568      // 8*4 = 32
#define ZR_BYTES  65600      // zeroes H1 + CCNT + SCNT
#define OFF_SEL   65600      // 8*16 = 128 (16B aligned)
#define OFF_BOX   65728      // 8*2000*16 = 256000 (16B aligned)
#define OFF_VALID 321728     // 8*2000*4 = 64000
#define OFF_SUP   385728     // 8*2000*32*8 = 4096000 (8B aligned)
#define OFF_CAND  385728     // overlay on sup (lifetime: gather->refine): 8*8192*8 = 524288
#define OFF_SELK  910016     // overlay on sup (lifetime: refine->rank): 8*4096*8 = 262144

__device__ __forceinline__ unsigned int xform(float f) {
    unsigned int b = __float_as_uint(f);
    return b ^ ((unsigned int)((int)b >> 31) | 0x80000000u);  // monotonic float->uint
}

// ---------------- Kernel A: per-batch 2048-bin hist of top-11 key bits ----------------
__global__ __launch_bounds__(256) void k_hist1(const float* __restrict__ cls,
                                               unsigned int* __restrict__ hist1) {
    int b = blockIdx.y, part = blockIdx.x, tid = threadIdx.x;
    __shared__ unsigned int h[2048];
    for (int i = tid; i < 2048; i += 256) h[i] = 0u;
    __syncthreads();
    const float4* base4 = (const float4*)(cls + (size_t)b * NTOT);
    const int n4 = NTOT / 4;
    int per = (n4 + GSPLIT - 1) / GSPLIT;
    int lo = part * per, hi = lo + per;
    if (hi > n4) hi = n4;
    for (int i = lo + tid; i < hi; i += 256) {
        float4 v = base4[i];
        atomicAdd(&h[xform(v.x) >> 21], 1u);
        atomicAdd(&h[xform(v.y) >> 21], 1u);
        atomicAdd(&h[xform(v.z) >> 21], 1u);
        atomicAdd(&h[xform(v.w) >> 21], 1u);
    }
    __syncthreads();
    unsigned int* gh = hist1 + b * 2048;
    for (int i = tid; i < 2048; i += 256)
        if (h[i]) atomicAdd(&gh[i], h[i]);
}

// ---------------- Kernel B: suffix-scan hist1, find threshold bin ----------------
__global__ __launch_bounds__(1024) void k_scan1(const unsigned int* __restrict__ hist1,
                                                uint4* __restrict__ selinfo) {
    int b = blockIdx.x, tid = threadIdx.x;
    __shared__ unsigned int sa[2048], sb[2048];
    const unsigned int* h = hist1 + b * 2048;
    sa[tid] = h[tid];
    sa[tid + 1024] = h[tid + 1024];
    unsigned int* src = sa; unsigned int* dst = sb;
    for (int d = 1; d < 2048; d <<= 1) {
        __syncthreads();
        dst[tid] = src[tid] + ((tid + d < 2048) ? src[tid + d] : 0u);
        int i2 = tid + 1024;
        dst[i2] = src[i2] + ((i2 + d < 2048) ? src[i2 + d] : 0u);
        unsigned int* t = src; src = dst; dst = t;
    }
    __syncthreads();
    #pragma unroll
    for (int k = 0; k < 2; ++k) {
        int i = tid + k * 1024;
        unsigned int c = src[i];
        unsigned int cn = (i < 2047) ? src[i + 1] : 0u;
        if (c >= KSEL && cn < KSEL)
            selinfo[b] = make_uint4((unsigned int)i, cn, KSEL - cn, 0u);
    }
}

// -------- Kernel C: gather all keys with bin >= threshold bin (block-local compaction) --------
__global__ __launch_bounds__(256) void k_gather(const float* __restrict__ cls,
                                                const uint4* __restrict__ selinfo,
                                                unsigned long long* __restrict__ cand,
                                                unsigned int* __restrict__ ccnt) {
    int b = blockIdx.y, part = blockIdx.x, tid = threadIdx.x;
    unsigned int bin = selinfo[b].x;
    __shared__ unsigned long long lbuf[1024];
    __shared__ unsigned int lcnt, gbase;
    if (tid == 0) lcnt = 0u;
    __syncthreads();
    const float4* base4 = (const float4*)(cls + (size_t)b * NTOT);
    const int n4 = NTOT / 4;
    int per = (n4 + GSPLIT - 1) / GSPLIT;
    int lo = part * per, hi = lo + per;
    if (hi > n4) hi = n4;
    for (int i = lo + tid; i < hi; i += 256) {
        float4 v = base4[i];
        float vals[4] = {v.x, v.y, v.z, v.w};
        int idx0 = i * 4;
        #pragma unroll
        for (int q = 0; q < 4; ++q) {
            unsigned int u = xform(vals[q]);
            if ((u >> 21) >= bin) {
                int idx = idx0 + q;
                int a = idx / HWSZ;
                int hw = idx - a * HWSZ;
                unsigned int n = (unsigned int)(hw * NA + a);
                unsigned int pos = atomicAdd(&lcnt, 1u);
                if (pos < 1024u)
                    lbuf[pos] = ((unsigned long long)u << 32) | (unsigned long long)(~n);
            }
        }
    }
    __syncthreads();
    if (tid == 0) {
        unsigned int c = lcnt < 1024u ? lcnt : 1024u;
        gbase = atomicAdd(&ccnt[b], c);
    }
    __syncthreads();
    unsigned int c = lcnt < 1024u ? lcnt : 1024u;
    unsigned int gb = gbase;
    for (unsigned int i = tid; i < c; i += 256) {
        unsigned int p = gb + i;
        if (p < CANDCAP) cand[(size_t)b * CANDCAP + p] = lbuf[i];
    }
}

// -------- Kernel D: refine exact threshold + compact selected keys (no sort) --------
__global__ __launch_bounds__(1024) void k_refine(const unsigned long long* __restrict__ cand,
                                                 const unsigned int* __restrict__ ccnt,
                                                 const uint4* __restrict__ selinfo,
                                                 unsigned long long* __restrict__ selk,
                                                 unsigned int* __restrict__ scnt) {
    int b = blockIdx.x;
    int tid = threadIdx.x;
    __shared__ unsigned int sa[2048], sb[2048];
    __shared__ unsigned int acnt, shT;
    uint4 si = selinfo[b];
    unsigned int bin = si.x, krem = si.z;
    unsigned int m = ccnt[b];
    if (m > CANDCAP) m = CANDCAP;
    const unsigned long long* cb = cand + (size_t)b * CANDCAP;

    // sub-bin histogram (bits [20:10]) of in-bin candidates
    sa[tid] = 0u; sa[tid + 1024] = 0u;
    if (tid == 0) acnt = 0u;
    __syncthreads();
    for (unsigned int i = tid; i < m; i += 1024) {
        unsigned int u = (unsigned int)(cb[i] >> 32);
        if ((u >> 21) == bin) atomicAdd(&sa[(u >> 10) & 2047u], 1u);
    }
    // suffix scan
    unsigned int* src = sa; unsigned int* dst = sb;
    for (int d = 1; d < 2048; d <<= 1) {
        __syncthreads();
        dst[tid] = src[tid] + ((tid + d < 2048) ? src[tid + d] : 0u);
        int i2 = tid + 1024;
        dst[i2] = src[i2] + ((i2 + d < 2048) ? src[i2 + d] : 0u);
        unsigned int* t = src; src = dst; dst = t;
    }
    __syncthreads();
    #pragma unroll
    for (int k = 0; k < 2; ++k) {
        int i = tid + k * 1024;
        unsigned int c = src[i];
        unsigned int cn = (i < 2047) ? src[i + 1] : 0u;
        if (c >= krem && cn < krem)
            shT = (bin << 21) | ((unsigned int)i << 10);
    }
    __syncthreads();
    unsigned int T = shT;

    // compact keys >= T into selk via wave-ballot (order irrelevant — rank fixes it)
    int lane = tid & 63;
    unsigned long long lmask = (1ULL << lane) - 1ULL;
    unsigned int mr = (m + 1023u) & ~1023u;
    unsigned long long* sout = selk + (size_t)b * SELCAP;
    for (unsigned int i = tid; i < mr; i += 1024) {
        bool pred = false;
        unsigned long long key = 0ULL;
        if (i < m) {
            key = cb[i];
            pred = ((unsigned int)(key >> 32)) >= T;
        }
        unsigned long long mask = __ballot(pred);
        unsigned int cw = (unsigned int)__popcll(mask);
        unsigned int base = 0u;
        if (lane == 0 && cw) base = atomicAdd(&acnt, cw);
        base = __shfl(base, 0, 64);
        if (pred) {
            unsigned int pos = base + (unsigned int)__popcll(mask & lmask);
            if (pos < SELCAP) sout[pos] = key;
        }
    }
    __syncthreads();
    if (tid == 0) scnt[b] = (acnt < SELCAP) ? acnt : SELCAP;
}

// -------- Kernel E: rank-by-count + box decode, writes at out position = rank --------
__global__ __launch_bounds__(256) void k_rank_decode(
        const unsigned long long* __restrict__ selk,
        const unsigned int* __restrict__ scnt,
        const float* __restrict__ regs,
        const float* __restrict__ anchors,
        const int* __restrict__ img_h,
        const int* __restrict__ img_w,
        float* __restrict__ out_scores,
        float4* __restrict__ boxes_ws,
        unsigned int* __restrict__ valid_ws) {
    int b = blockIdx.y;
    int tid = threadIdx.x;
    int lane = tid & 63;
    unsigned int sc = scnt[b];
    if (sc > SELCAP) sc = SELCAP;
    unsigned int r = blockIdx.x * 256 + tid;
    if (blockIdx.x * 256 >= sc) return;   // uniform early-out for spare blocks
    const unsigned long long* sb_ = selk + (size_t)b * SELCAP;
    unsigned long long mykey = (r < sc) ? sb_[r] : 0ULL;

    // rank = #{selected keys > mykey}; stream columns 64 at a time, broadcast via readlane
    unsigned int cnt = 0u;
    for (unsigned int base = 0; base < sc; base += 64) {
        unsigned long long kj = 0ULL;
        if (base + (unsigned int)lane < sc) kj = sb_[base + lane];
        unsigned int klo = (unsigned int)kj;
        unsigned int khi = (unsigned int)(kj >> 32);
        #pragma unroll
        for (int t = 0; t < 64; ++t) {
            unsigned int lo = (unsigned int)__builtin_amdgcn_readlane((int)klo, t);
            unsigned int hi = (unsigned int)__builtin_amdgcn_readlane((int)khi, t);
            unsigned long long kt = ((unsigned long long)hi << 32) | (unsigned long long)lo;
            cnt += (kt > mykey) ? 1u : 0u;
        }
    }
    if (r >= sc || cnt >= KSEL) return;

    int hv = img_h[0];
    int wv = img_w[0];
    float himg = (hv > 0 && hv < 100000) ? (float)hv : __int_as_float(hv);
    float wimg = (wv > 0 && wv < 100000) ? (float)wv : __int_as_float(wv);

    unsigned int u = (unsigned int)(mykey >> 32);
    unsigned int n = ~((unsigned int)mykey);
    unsigned int bits = (u & 0x80000000u) ? (u & 0x7FFFFFFFu) : ~u;
    float score = __uint_as_float(bits);
    int a = (int)(n % NA);
    int hw = (int)(n / NA);
    const float* rp = regs + ((size_t)b * (4 * NA) + 4 * a) * HWSZ + hw;
    float dx = rp[0 * HWSZ];
    float dy = rp[1 * HWSZ];
    float dh = rp[2 * HWSZ];
    float dw = rp[3 * HWSZ];
    const float* ap = anchors + ((size_t)b * NTOT + n) * 4;
    float ax1 = ap[0], ay1 = ap[1], ax2 = ap[2], ay2 = ap[3];
    float ahh = ay2 - ay1;
    float aww = ax2 - ax1;
    float cx = aww * 0.5f;
    float cy = ahh * 0.5f;
    float px = cx + dx * aww;
    float py = cy + dy * ahh;
    dh = fminf(dh, LOG_MAX_F);
    dw = fminf(dw, LOG_MAX_F);
    float ph = expf(dh) * ahh;
    float pw = expf(dw) * aww;
    float x1 = px - pw * 0.5f;
    float y1 = py - ph * 0.5f;
    float x2 = px + pw * 0.5f;
    float y2 = py + ph * 0.5f;
    float bwv = fminf(fmaxf(x2, 0.f), wimg) - fminf(fmaxf(x1, 0.f), wimg);
    float bhv = fminf(fmaxf(y2, 0.f), himg) - fminf(fmaxf(y1, 0.f), himg);
    unsigned int valid = (bwv >= 16.f && bhv >= 16.f) ? 1u : 0u;
    size_t o = (size_t)b * KSEL + cnt;   // output position = rank
    out_scores[o] = score;
    boxes_ws[o] = make_float4(x1, y1, x2, y2);
    valid_ws[o] = valid;
}

// -------- Kernel 3: suppression bitmask matrix (rows x 64-col words), 256 thr --------
__global__ __launch_bounds__(256) void k_supmat(const float4* __restrict__ boxes_ws,
                                                unsigned long long* __restrict__ sup) {
    int ct = blockIdx.x;    // col tile 0..31
    int rt = blockIdx.y;    // row super-tile 0..7 (256 rows each)
    int b  = blockIdx.z;
    int tid = threadIdx.x;
    __shared__ float4 colbox[64];
    int j0 = ct * 64;
    if (tid < 64) {
        int jl = j0 + tid;
        colbox[tid] = (jl < KSEL) ? boxes_ws[(size_t)b * KSEL + jl]
                                  : make_float4(0.f, 0.f, 0.f, 0.f);
    }
    __syncthreads();
    int i = rt * 256 + tid;
    if (i >= KSEL) return;
    float4 bi = boxes_ws[(size_t)b * KSEL + i];
    float area_i = (bi.z - bi.x) * (bi.w - bi.y);
    unsigned long long word = 0ULL;
    #pragma unroll 8
    for (int jj = 0; jj < 64; ++jj) {
        int j = j0 + jj;
        float4 bj = colbox[jj];
        float area_j = (bj.z - bj.x) * (bj.w - bj.y);
        float ix1 = fmaxf(bi.x, bj.x);
        float iy1 = fmaxf(bi.y, bj.y);
        float ix2 = fminf(bi.z, bj.z);
        float iy2 = fminf(bi.w, bj.w);
        float iw = fmaxf(ix2 - ix1, 0.f);
        float ih = fmaxf(iy2 - iy1, 0.f);
        float inter = iw * ih;
        float uni = area_i + area_j - inter;
        float iou = inter / fmaxf(uni, 1e-6f);
        bool s = (j > i) && (j < KSEL) && (iou > 0.7f);
        if (s) word |= (1ULL << jj);
    }
    sup[((size_t)b * KSEL + i) * 32 + ct] = word;
}

// ---- Kernel 4: word-tile greedy scan — ff1 sparse chain, lazy accw, depth-2 prefetch ----
#define LOAD_TILE(wnext, buf)                                                \
    {                                                                        \
        int gbase_ = (wnext) * 2048;                                         \
        _Pragma("unroll")                                                    \
        for (int k = 0; k < 8; ++k) {                                        \
            int e_ = tid + k * 256;                                          \
            int row_ = (wnext) * 64 + (e_ >> 5);                             \
            buf[k] = (row_ < KSEL) ? srow[gbase_ + e_] : 0ULL;               \
        }                                                                    \
    }

#define PROCESS_TILE(w, buf)                                                 \
    {                                                                        \
        if (myword == (w)) {                                                 \
            _Pragma("unroll")                                                \
            for (int k = 0; k < 8; ++k)                                      \
                diag[(tid >> 5) + k * 8] = buf[k];                           \
        }                                                                    \
        __syncthreads();  /* diag ready; prior applies visible in accw */    \
        unsigned long long dval_ = diag[lane];                               \
        unsigned int dlo_ = (unsigned int)dval_;                             \
        unsigned int dhi_ = (unsigned int)(dval_ >> 32);                     \
        unsigned long long pend_ =                                           \
            ((unsigned long long)accw[(w) * 2 + 1] << 32)                    \
            | (unsigned long long)accw[(w) * 2];                             \
        unsigned long long c64_ = kws[w] & ~pend_;                           \
        unsigned int clo_ = __builtin_amdgcn_readfirstlane((unsigned int)c64_);        \
        unsigned int chi_ = __builtin_amdgcn_readfirstlane((unsigned int)(c64_ >> 32));\
        unsigned long long cur_ = ((unsigned long long)chi_ << 32)           \
                                  | (unsigned long long)clo_;                \
        if (cur_) {                                                          \
            unsigned long long rem_ = cur_;                                  \
            while (rem_) {  /* sparse greedy chain over surviving bits */    \
                int bit_ = __builtin_ctzll(rem_);                            \
                unsigned int lo_ = (unsigned int)__builtin_amdgcn_readlane((int)dlo_, bit_); \
                unsigned int hi_ = (unsigned int)__builtin_amdgcn_readlane((int)dhi_, bit_); \
                unsigned long long d_ = ((unsigned long long)hi_ << 32)      \
                                        | (unsigned long long)lo_;           \
                cur_ &= ~d_;                                                 \
                rem_ = cur_ & ~((2ULL << bit_) - 1ULL);                      \
            }                                                                \
            if (tid == 0) fin[w] = cur_;                                     \
            unsigned long long v_ = 0ULL;                                    \
            _Pragma("unroll")                                                \
            for (int k = 0; k < 8; ++k) {                                    \
                int row_ = (tid >> 5) + k * 8;                               \
                if ((cur_ >> row_) & 1ULL) v_ |= buf[k];                     \
            }                                                                \
            v_ |= __shfl_xor(v_, 32, 64);                                    \
            if (lane < 32 && v_) {                                           \
                atomicOr(&accw[myword * 2], (unsigned int)v_);               \
                atomicOr(&accw[myword * 2 + 1], (unsigned int)(v_ >> 32));   \
            }                                                                \
        } else if (tid == 0) {                                               \
            fin[w] = 0ULL;                                                   \
        }                                                                    \
    }

__global__ __launch_bounds__(256) void k_nms_scan(const unsigned long long* __restrict__ sup,
                                                  const unsigned int* __restrict__ valid_ws,
                                                  const float4* __restrict__ boxes_ws,
                                                  float* __restrict__ out_boxes,
                                                  float* __restrict__ out_keep) {
    int b = blockIdx.x;
    int tid = threadIdx.x;
    int lane = tid & 63;
    int myword = tid & 31;
    __shared__ unsigned long long kws[32];     // initial validity words (read-only in loop)
    __shared__ unsigned long long fin[32];     // final keep words
    __shared__ unsigned long long diag[64];    // current tile's word-w column
    __shared__ unsigned int accw[64];          // lazy suppression accumulator (monotone)
    const unsigned long long* srow = sup + (size_t)b * KSEL * 32;

    if (tid < 32) {
        unsigned long long kw = 0ULL;
        const uint4* vv = (const uint4*)(valid_ws + (size_t)b * KSEL);
        #pragma unroll 4
        for (int q = 0; q < 16; ++q) {
            uint4 x = vv[tid * 16 + q];   // tid=31,q>=4 reads past 2000 — bits masked below
            int base = q * 4;
            if (x.x) kw |= 1ULL << (base + 0);
            if (x.y) kw |= 1ULL << (base + 1);
            if (x.z) kw |= 1ULL << (base + 2);
            if (x.w) kw |= 1ULL << (base + 3);
        }
        if (tid == 31) kw &= 0xFFFFULL;   // rows 2000..2047 invalid
        kws[tid] = kw;
    }
    if (tid < 64) accw[tid] = 0u;

    // depth-2 prefetch: A holds even tiles, B odd tiles
    unsigned long long A[8], B[8];
    LOAD_TILE(0, A);
    LOAD_TILE(1, B);

    for (int t = 0; t < 16; ++t) {
        int w = 2 * t;
        PROCESS_TILE(w, A);
        if (w + 2 < 32) LOAD_TILE(w + 2, A);   // issue ~1 iter before use
        PROCESS_TILE(w + 1, B);
        if (w + 3 < 32) LOAD_TILE(w + 3, B);
    }
    __syncthreads();

    for (int r = tid; r < KSEL; r += 256) {
        float kf = (float)((fin[r >> 6] >> (r & 63)) & 1ULL);
        size_t o = (size_t)b * KSEL + r;
        out_keep[o] = kf;
        float4 bx = boxes_ws[o];
        float* ob = out_boxes + o * 4;
        ob[0] = bx.x * kf;
        ob[1] = bx.y * kf;
        ob[2] = bx.z * kf;
        ob[3] = bx.w * kf;
    }
}

extern "C" void kernel_launch(void* const* d_in, const int* in_sizes, int n_in,
                              void* d_out, int out_size, void* d_ws, size_t ws_size,
                              hipStream_t stream) {
    const float* cls     = (const float*)d_in[0];
    const float* regs    = (const float*)d_in[1];
    const float* anchors = (const float*)d_in[2];
    const int*   img_h   = (const int*)d_in[3];
    const int*   img_w   = (const int*)d_in[4];

    float* out = (float*)d_out;
    float* out_boxes  = out;            // 8*2000*4
    float* out_scores = out + 64000;    // 8*2000
    float* out_keep   = out + 80000;    // 8*2000

    char* ws = (char*)d_ws;
    unsigned int* hist1      = (unsigned int*)(ws + OFF_H1);
    unsigned int* ccnt       = (unsigned int*)(ws + OFF_CCNT);
    unsigned int* scnt       = (unsigned int*)(ws + OFF_SCNT);
    uint4* selinfo           = (uint4*)(ws + OFF_SEL);
    float4* boxes_ws         = (float4*)(ws + OFF_BOX);
    unsigned int* valid_ws   = (unsigned int*)(ws + OFF_VALID);
    unsigned long long* sup  = (unsigned long long*)(ws + OFF_SUP);
    unsigned long long* cand = (unsigned long long*)(ws + OFF_CAND);
    unsigned long long* selk = (unsigned long long*)(ws + OFF_SELK);

    hipMemsetAsync(ws, 0, ZR_BYTES, stream);
    k_hist1<<<dim3(GSPLIT, NBATCH), 256, 0, stream>>>(cls, hist1);
    k_scan1<<<NBATCH, 1024, 0, stream>>>(hist1, selinfo);
    k_gather<<<dim3(GSPLIT, NBATCH), 256, 0, stream>>>(cls, selinfo, cand, ccnt);
    k_refine<<<NBATCH, 1024, 0, stream>>>(cand, ccnt, selinfo, selk, scnt);
    k_rank_decode<<<dim3(10, NBATCH), 256, 0, stream>>>(selk, scnt, regs, anchors,
                                                        img_h, img_w, out_scores,
                                                        boxes_ws, valid_ws);
    k_supmat<<<dim3(32, 8, NBATCH), 256, 0, stream>>>(boxes_ws, sup);
    k_nms_scan<<<NBATCH, 256, 0, stream>>>(sup, valid_ws, boxes_ws, out_boxes, out_keep);
}

// Round 9
// 199.565 us; speedup vs baseline: 3.1418x; 1.1038x over previous
//
#include <hip/hip_runtime.h>

// Problem constants (B=8, A=3, H=200, W=304)
#define HWSZ 60800      // H*W
#define NA 3
#define NTOT 182400     // A*H*W
#define KSEL 2000
#define CANDCAP 8192
#define SELCAP 4096
#define NBATCH 8
#define GSPLIT 128
#define LOG_MAX_F 4.135166556742356f   // log(1000/16) rounded to fp32

// ---- workspace layout (bytes) ----
#define OFF_H1    0          // 8*2048*4 = 65536
#define OFF_CCNT  65536      // 8*4 = 32
#define OFF_SCNT  65568      // 8*4 = 32
#define ZR_BYTES  65600      // zeroes H1 + CCNT + SCNT
#define OFF_SEL   65600      // 8*16 = 128 (16B aligned)
#define OFF_BOX   65728      // 8*2000*16 = 256000 (16B aligned)
#define OFF_VALID 321728     // 8*2000*4 = 64000
#define OFF_SUP   385728     // 8*2000*32*8 = 4096000 (8B aligned)
#define OFF_CAND  385728     // overlay on sup (lifetime: gather->refine): 8*8192*8 = 524288
#define OFF_SELK  910016     // overlay on sup (lifetime: refine->rank): 8*4096*8 = 262144

__device__ __forceinline__ unsigned int xform(float f) {
    unsigned int b = __float_as_uint(f);
    return b ^ ((unsigned int)((int)b >> 31) | 0x80000000u);  // monotonic float->uint
}

// ---------------- Kernel A: per-batch 2048-bin hist of top-11 key bits ----------------
__global__ __launch_bounds__(256) void k_hist1(const float* __restrict__ cls,
                                               unsigned int* __restrict__ hist1) {
    int b = blockIdx.y, part = blockIdx.x, tid = threadIdx.x;
    __shared__ unsigned int h[2048];
    for (int i = tid; i < 2048; i += 256) h[i] = 0u;
    __syncthreads();
    const float4* base4 = (const float4*)(cls + (size_t)b * NTOT);
    const int n4 = NTOT / 4;
    int per = (n4 + GSPLIT - 1) / GSPLIT;
    int lo = part * per, hi = lo + per;
    if (hi > n4) hi = n4;
    for (int i = lo + tid; i < hi; i += 256) {
        float4 v = base4[i];
        atomicAdd(&h[xform(v.x) >> 21], 1u);
        atomicAdd(&h[xform(v.y) >> 21], 1u);
        atomicAdd(&h[xform(v.z) >> 21], 1u);
        atomicAdd(&h[xform(v.w) >> 21], 1u);
    }
    __syncthreads();
    unsigned int* gh = hist1 + b * 2048;
    for (int i = tid; i < 2048; i += 256)
        if (h[i]) atomicAdd(&gh[i], h[i]);
}

// ---------------- Kernel B: suffix-scan hist1, find threshold bin ----------------
__global__ __launch_bounds__(1024) void k_scan1(const unsigned int* __restrict__ hist1,
                                                uint4* __restrict__ selinfo) {
    int b = blockIdx.x, tid = threadIdx.x;
    __shared__ unsigned int sa[2048], sb[2048];
    const unsigned int* h = hist1 + b * 2048;
    sa[tid] = h[tid];
    sa[tid + 1024] = h[tid + 1024];
    unsigned int* src = sa; unsigned int* dst = sb;
    for (int d = 1; d < 2048; d <<= 1) {
        __syncthreads();
        dst[tid] = src[tid] + ((tid + d < 2048) ? src[tid + d] : 0u);
        int i2 = tid + 1024;
        dst[i2] = src[i2] + ((i2 + d < 2048) ? src[i2 + d] : 0u);
        unsigned int* t = src; src = dst; dst = t;
    }
    __syncthreads();
    #pragma unroll
    for (int k = 0; k < 2; ++k) {
        int i = tid + k * 1024;
        unsigned int c = src[i];
        unsigned int cn = (i < 2047) ? src[i + 1] : 0u;
        if (c >= KSEL && cn < KSEL)
            selinfo[b] = make_uint4((unsigned int)i, cn, KSEL - cn, 0u);
    }
}

// -------- Kernel C: gather all keys with bin >= threshold bin (block-local compaction) --------
__global__ __launch_bounds__(256) void k_gather(const float* __restrict__ cls,
                                                const uint4* __restrict__ selinfo,
                                                unsigned long long* __restrict__ cand,
                                                unsigned int* __restrict__ ccnt) {
    int b = blockIdx.y, part = blockIdx.x, tid = threadIdx.x;
    unsigned int bin = selinfo[b].x;
    __shared__ unsigned long long lbuf[1024];
    __shared__ unsigned int lcnt, gbase;
    if (tid == 0) lcnt = 0u;
    __syncthreads();
    const float4* base4 = (const float4*)(cls + (size_t)b * NTOT);
    const int n4 = NTOT / 4;
    int per = (n4 + GSPLIT - 1) / GSPLIT;
    int lo = part * per, hi = lo + per;
    if (hi > n4) hi = n4;
    for (int i = lo + tid; i < hi; i += 256) {
        float4 v = base4[i];
        float vals[4] = {v.x, v.y, v.z, v.w};
        int idx0 = i * 4;
        #pragma unroll
        for (int q = 0; q < 4; ++q) {
            unsigned int u = xform(vals[q]);
            if ((u >> 21) >= bin) {
                int idx = idx0 + q;
                int a = idx / HWSZ;
                int hw = idx - a * HWSZ;
                unsigned int n = (unsigned int)(hw * NA + a);
                unsigned int pos = atomicAdd(&lcnt, 1u);
                if (pos < 1024u)
                    lbuf[pos] = ((unsigned long long)u << 32) | (unsigned long long)(~n);
            }
        }
    }
    __syncthreads();
    if (tid == 0) {
        unsigned int c = lcnt < 1024u ? lcnt : 1024u;
        gbase = atomicAdd(&ccnt[b], c);
    }
    __syncthreads();
    unsigned int c = lcnt < 1024u ? lcnt : 1024u;
    unsigned int gb = gbase;
    for (unsigned int i = tid; i < c; i += 256) {
        unsigned int p = gb + i;
        if (p < CANDCAP) cand[(size_t)b * CANDCAP + p] = lbuf[i];
    }
}

// -------- Kernel D: refine exact threshold + compact selected keys (no sort) --------
__global__ __launch_bounds__(1024) void k_refine(const unsigned long long* __restrict__ cand,
                                                 const unsigned int* __restrict__ ccnt,
                                                 const uint4* __restrict__ selinfo,
                                                 unsigned long long* __restrict__ selk,
                                                 unsigned int* __restrict__ scnt) {
    int b = blockIdx.x;
    int tid = threadIdx.x;
    __shared__ unsigned int sa[2048], sb[2048];
    __shared__ unsigned int acnt, shT;
    uint4 si = selinfo[b];
    unsigned int bin = si.x, krem = si.z;
    unsigned int m = ccnt[b];
    if (m > CANDCAP) m = CANDCAP;
    const unsigned long long* cb = cand + (size_t)b * CANDCAP;

    // sub-bin histogram (bits [20:10]) of in-bin candidates
    sa[tid] = 0u; sa[tid + 1024] = 0u;
    if (tid == 0) acnt = 0u;
    __syncthreads();
    for (unsigned int i = tid; i < m; i += 1024) {
        unsigned int u = (unsigned int)(cb[i] >> 32);
        if ((u >> 21) == bin) atomicAdd(&sa[(u >> 10) & 2047u], 1u);
    }
    // suffix scan
    unsigned int* src = sa; unsigned int* dst = sb;
    for (int d = 1; d < 2048; d <<= 1) {
        __syncthreads();
        dst[tid] = src[tid] + ((tid + d < 2048) ? src[tid + d] : 0u);
        int i2 = tid + 1024;
        dst[i2] = src[i2] + ((i2 + d < 2048) ? src[i2 + d] : 0u);
        unsigned int* t = src; src = dst; dst = t;
    }
    __syncthreads();
    #pragma unroll
    for (int k = 0; k < 2; ++k) {
        int i = tid + k * 1024;
        unsigned int c = src[i];
        unsigned int cn = (i < 2047) ? src[i + 1] : 0u;
        if (c >= krem && cn < krem)
            shT = (bin << 21) | ((unsigned int)i << 10);
    }
    __syncthreads();
    unsigned int T = shT;

    // compact keys >= T into selk via wave-ballot (order irrelevant — rank fixes it)
    int lane = tid & 63;
    unsigned long long lmask = (1ULL << lane) - 1ULL;
    unsigned int mr = (m + 1023u) & ~1023u;
    unsigned long long* sout = selk + (size_t)b * SELCAP;
    for (unsigned int i = tid; i < mr; i += 1024) {
        bool pred = false;
        unsigned long long key = 0ULL;
        if (i < m) {
            key = cb[i];
            pred = ((unsigned int)(key >> 32)) >= T;
        }
        unsigned long long mask = __ballot(pred);
        unsigned int cw = (unsigned int)__popcll(mask);
        unsigned int base = 0u;
        if (lane == 0 && cw) base = atomicAdd(&acnt, cw);
        base = __shfl(base, 0, 64);
        if (pred) {
            unsigned int pos = base + (unsigned int)__popcll(mask & lmask);
            if (pos < SELCAP) sout[pos] = key;
        }
    }
    __syncthreads();
    if (tid == 0) scnt[b] = (acnt < SELCAP) ? acnt : SELCAP;
}

// -------- Kernel E: rank-by-count (4 threads/key) + box decode at position = rank --------
__global__ __launch_bounds__(256) void k_rank_decode(
        const unsigned long long* __restrict__ selk,
        const unsigned int* __restrict__ scnt,
        const float* __restrict__ regs,
        const float* __restrict__ anchors,
        const int* __restrict__ img_h,
        const int* __restrict__ img_w,
        float* __restrict__ out_scores,
        float4* __restrict__ boxes_ws,
        unsigned int* __restrict__ valid_ws) {
    int b = blockIdx.y;
    int tid = threadIdx.x;
    unsigned int sc = scnt[b];
    if (sc > SELCAP) sc = SELCAP;
    unsigned int kbase = blockIdx.x * 64;
    if (kbase >= sc) return;   // uniform early-out for spare blocks
    int ki = tid & 63;         // key slot within block (== lane)
    int q = tid >> 6;          // column-quarter 0..3 (== wave id)
    int lane = tid & 63;
    const unsigned long long* sb_ = selk + (size_t)b * SELCAP;
    unsigned int r = kbase + (unsigned int)ki;
    unsigned long long mykey = (r < sc) ? sb_[r] : 0ULL;

    // quarter column range [lo, hi); qs is a multiple of 64 with 4*qs >= sc
    unsigned int qs = ((sc + 255u) >> 8) << 6;
    unsigned int lo = (unsigned int)q * qs;
    unsigned int hi = lo + qs;
    if (hi > sc) hi = sc;

    unsigned int cnt = 0u;
    for (unsigned int base = lo; base < hi; base += 64) {
        unsigned long long kj = 0ULL;   // 0 > mykey is false for any real key
        if (base + (unsigned int)lane < hi) kj = sb_[base + lane];
        unsigned int klo = (unsigned int)kj;
        unsigned int khi = (unsigned int)(kj >> 32);
        #pragma unroll
        for (int t = 0; t < 64; ++t) {
            unsigned int lo_ = (unsigned int)__builtin_amdgcn_readlane((int)klo, t);
            unsigned int hi_ = (unsigned int)__builtin_amdgcn_readlane((int)khi, t);
            unsigned long long kt = ((unsigned long long)hi_ << 32) | (unsigned long long)lo_;
            cnt += (kt > mykey) ? 1u : 0u;
        }
    }
    __shared__ unsigned int cntsh[4][64];
    cntsh[q][ki] = cnt;
    __syncthreads();
    if (tid >= 64) return;
    unsigned int rank = cntsh[0][ki] + cntsh[1][ki] + cntsh[2][ki] + cntsh[3][ki];
    if (r >= sc || rank >= KSEL) return;

    int hv = img_h[0];
    int wv = img_w[0];
    float himg = (hv > 0 && hv < 100000) ? (float)hv : __int_as_float(hv);
    float wimg = (wv > 0 && wv < 100000) ? (float)wv : __int_as_float(wv);

    unsigned int u = (unsigned int)(mykey >> 32);
    unsigned int n = ~((unsigned int)mykey);
    unsigned int bits = (u & 0x80000000u) ? (u & 0x7FFFFFFFu) : ~u;
    float score = __uint_as_float(bits);
    int a = (int)(n % NA);
    int hw = (int)(n / NA);
    const float* rp = regs + ((size_t)b * (4 * NA) + 4 * a) * HWSZ + hw;
    float dx = rp[0 * HWSZ];
    float dy = rp[1 * HWSZ];
    float dh = rp[2 * HWSZ];
    float dw = rp[3 * HWSZ];
    const float* ap = anchors + ((size_t)b * NTOT + n) * 4;
    float ax1 = ap[0], ay1 = ap[1], ax2 = ap[2], ay2 = ap[3];
    float ahh = ay2 - ay1;
    float aww = ax2 - ax1;
    float cx = aww * 0.5f;
    float cy = ahh * 0.5f;
    float px = cx + dx * aww;
    float py = cy + dy * ahh;
    dh = fminf(dh, LOG_MAX_F);
    dw = fminf(dw, LOG_MAX_F);
    float ph = expf(dh) * ahh;
    float pw = expf(dw) * aww;
    float x1 = px - pw * 0.5f;
    float y1 = py - ph * 0.5f;
    float x2 = px + pw * 0.5f;
    float y2 = py + ph * 0.5f;
    float bwv = fminf(fmaxf(x2, 0.f), wimg) - fminf(fmaxf(x1, 0.f), wimg);
    float bhv = fminf(fmaxf(y2, 0.f), himg) - fminf(fmaxf(y1, 0.f), himg);
    unsigned int valid = (bwv >= 16.f && bhv >= 16.f) ? 1u : 0u;
    size_t o = (size_t)b * KSEL + rank;   // output position = rank
    out_scores[o] = score;
    boxes_ws[o] = make_float4(x1, y1, x2, y2);
    valid_ws[o] = valid;
}

// -------- Kernel 3: suppression bitmask matrix (rows x 64-col words), 256 thr --------
__global__ __launch_bounds__(256) void k_supmat(const float4* __restrict__ boxes_ws,
                                                unsigned long long* __restrict__ sup) {
    int ct = blockIdx.x;    // col tile 0..31
    int rt = blockIdx.y;    // row super-tile 0..7 (256 rows each)
    int b  = blockIdx.z;
    int tid = threadIdx.x;
    __shared__ float4 colbox[64];
    int j0 = ct * 64;
    if (tid < 64) {
        int jl = j0 + tid;
        colbox[tid] = (jl < KSEL) ? boxes_ws[(size_t)b * KSEL + jl]
                                  : make_float4(0.f, 0.f, 0.f, 0.f);
    }
    __syncthreads();
    int i = rt * 256 + tid;
    if (i >= KSEL) return;
    float4 bi = boxes_ws[(size_t)b * KSEL + i];
    float area_i = (bi.z - bi.x) * (bi.w - bi.y);
    unsigned long long word = 0ULL;
    #pragma unroll 8
    for (int jj = 0; jj < 64; ++jj) {
        int j = j0 + jj;
        float4 bj = colbox[jj];
        float area_j = (bj.z - bj.x) * (bj.w - bj.y);
        float ix1 = fmaxf(bi.x, bj.x);
        float iy1 = fmaxf(bi.y, bj.y);
        float ix2 = fminf(bi.z, bj.z);
        float iy2 = fminf(bi.w, bj.w);
        float iw = fmaxf(ix2 - ix1, 0.f);
        float ih = fmaxf(iy2 - iy1, 0.f);
        float inter = iw * ih;
        float uni = area_i + area_j - inter;
        float iou = inter / fmaxf(uni, 1e-6f);
        bool s = (j > i) && (j < KSEL) && (iou > 0.7f);
        if (s) word |= (1ULL << jj);
    }
    sup[((size_t)b * KSEL + i) * 32 + ct] = word;
}

// ---- Kernel 4: word-tile greedy scan — nz-masked ff1 chain, lazy accw, depth-2 prefetch ----
#define LOAD_TILE(wnext, buf)                                                \
    {                                                                        \
        int gbase_ = (wnext) * 2048;                                         \
        _Pragma("unroll")                                                    \
        for (int k = 0; k < 8; ++k) {                                        \
            int e_ = tid + k * 256;                                          \
            int row_ = (wnext) * 64 + (e_ >> 5);                             \
            buf[k] = (row_ < KSEL) ? srow[gbase_ + e_] : 0ULL;               \
        }                                                                    \
    }

#define PROCESS_TILE(w, buf)                                                 \
    {                                                                        \
        if (myword == (w)) {                                                 \
            _Pragma("unroll")                                                \
            for (int k = 0; k < 8; ++k)                                      \
                diag[(tid >> 5) + k * 8] = buf[k];                           \
        }                                                                    \
        __syncthreads();  /* diag ready; prior applies visible in accw */    \
        unsigned long long dval_ = diag[lane];                               \
        unsigned long long nz_ = __ballot(dval_ != 0ULL);                    \
        unsigned int dlo_ = (unsigned int)dval_;                             \
        unsigned int dhi_ = (unsigned int)(dval_ >> 32);                     \
        unsigned long long pend_ =                                           \
            ((unsigned long long)accw[(w) * 2 + 1] << 32)                    \
            | (unsigned long long)accw[(w) * 2];                             \
        unsigned long long c64_ = kws[w] & ~pend_;                           \
        unsigned int clo_ = __builtin_amdgcn_readfirstlane((unsigned int)c64_);        \
        unsigned int chi_ = __builtin_amdgcn_readfirstlane((unsigned int)(c64_ >> 32));\
        unsigned long long cur_ = ((unsigned long long)chi_ << 32)           \
                                  | (unsigned long long)clo_;                \
        if (cur_) {                                                          \
            /* only rows with nonzero diag can change cur — skip the rest */ \
            unsigned long long rem_ = cur_ & nz_;                            \
            while (rem_) {                                                   \
                int bit_ = __builtin_ctzll(rem_);                            \
                unsigned int lo_ = (unsigned int)__builtin_amdgcn_readlane((int)dlo_, bit_); \
                unsigned int hi_ = (unsigned int)__builtin_amdgcn_readlane((int)dhi_, bit_); \
                unsigned long long d_ = ((unsigned long long)hi_ << 32)      \
                                        | (unsigned long long)lo_;           \
                cur_ &= ~d_;                                                 \
                rem_ = cur_ & nz_ & ~((2ULL << bit_) - 1ULL);                \
            }                                                                \
            if (tid == 0) fin[w] = cur_;                                     \
            unsigned long long v_ = 0ULL;                                    \
            _Pragma("unroll")                                                \
            for (int k = 0; k < 8; ++k) {                                    \
                int row_ = (tid >> 5) + k * 8;                               \
                if ((cur_ >> row_) & 1ULL) v_ |= buf[k];                     \
            }                                                                \
            v_ |= __shfl_xor(v_, 32, 64);                                    \
            if (lane < 32 && v_) {                                           \
                atomicOr(&accw[myword * 2], (unsigned int)v_);               \
                atomicOr(&accw[myword * 2 + 1], (unsigned int)(v_ >> 32));   \
            }                                                                \
        } else if (tid == 0) {                                               \
            fin[w] = 0ULL;                                                   \
        }                                                                    \
    }

__global__ __launch_bounds__(256) void k_nms_scan(const unsigned long long* __restrict__ sup,
                                                  const unsigned int* __restrict__ valid_ws,
                                                  const float4* __restrict__ boxes_ws,
                                                  float* __restrict__ out_boxes,
                                                  float* __restrict__ out_keep) {
    int b = blockIdx.x;
    int tid = threadIdx.x;
    int lane = tid & 63;
    int myword = tid & 31;
    __shared__ unsigned long long kws[32];     // initial validity words (read-only in loop)
    __shared__ unsigned long long fin[32];     // final keep words
    __shared__ unsigned long long diag[64];    // current tile's word-w column
    __shared__ unsigned int accw[64];          // lazy suppression accumulator (monotone)
    const unsigned long long* srow = sup + (size_t)b * KSEL * 32;

    if (tid < 32) {
        unsigned long long kw = 0ULL;
        const uint4* vv = (const uint4*)(valid_ws + (size_t)b * KSEL);
        #pragma unroll 4
        for (int q = 0; q < 16; ++q) {
            uint4 x = vv[tid * 16 + q];   // tid=31,q>=4 reads past 2000 — bits masked below
            int base = q * 4;
            if (x.x) kw |= 1ULL << (base + 0);
            if (x.y) kw |= 1ULL << (base + 1);
            if (x.z) kw |= 1ULL << (base + 2);
            if (x.w) kw |= 1ULL << (base + 3);
        }
        if (tid == 31) kw &= 0xFFFFULL;   // rows 2000..2047 invalid
        kws[tid] = kw;
    }
    if (tid < 64) accw[tid] = 0u;

    // depth-2 prefetch: A holds even tiles, B odd tiles
    unsigned long long A[8], B[8];
    LOAD_TILE(0, A);
    LOAD_TILE(1, B);

    for (int t = 0; t < 16; ++t) {
        int w = 2 * t;
        PROCESS_TILE(w, A);
        if (w + 2 < 32) LOAD_TILE(w + 2, A);   // issue ~1 iter before use
        PROCESS_TILE(w + 1, B);
        if (w + 3 < 32) LOAD_TILE(w + 3, B);
    }
    __syncthreads();

    for (int r = tid; r < KSEL; r += 256) {
        float kf = (float)((fin[r >> 6] >> (r & 63)) & 1ULL);
        size_t o = (size_t)b * KSEL + r;
        out_keep[o] = kf;
        float4 bx = boxes_ws[o];
        float* ob = out_boxes + o * 4;
        ob[0] = bx.x * kf;
        ob[1] = bx.y * kf;
        ob[2] = bx.z * kf;
        ob[3] = bx.w * kf;
    }
}

extern "C" void kernel_launch(void* const* d_in, const int* in_sizes, int n_in,
                              void* d_out, int out_size, void* d_ws, size_t ws_size,
                              hipStream_t stream) {
    const float* cls     = (const float*)d_in[0];
    const float* regs    = (const float*)d_in[1];
    const float* anchors = (const float*)d_in[2];
    const int*   img_h   = (const int*)d_in[3];
    const int*   img_w   = (const int*)d_in[4];

    float* out = (float*)d_out;
    float* out_boxes  = out;            // 8*2000*4
    float* out_scores = out + 64000;    // 8*2000
    float* out_keep   = out + 80000;    // 8*2000

    char* ws = (char*)d_ws;
    unsigned int* hist1      = (unsigned int*)(ws + OFF_H1);
    unsigned int* ccnt       = (unsigned int*)(ws + OFF_CCNT);
    unsigned int* scnt       = (unsigned int*)(ws + OFF_SCNT);
    uint4* selinfo           = (uint4*)(ws + OFF_SEL);
    float4* boxes_ws         = (float4*)(ws + OFF_BOX);
    unsigned int* valid_ws   = (unsigned int*)(ws + OFF_VALID);
    unsigned long long* sup  = (unsigned long long*)(ws + OFF_SUP);
    unsigned long long* cand = (unsigned long long*)(ws + OFF_CAND);
    unsigned long long* selk = (unsigned long long*)(ws + OFF_SELK);

    hipMemsetAsync(ws, 0, ZR_BYTES, stream);
    k_hist1<<<dim3(GSPLIT, NBATCH), 256, 0, stream>>>(cls, hist1);
    k_scan1<<<NBATCH, 1024, 0, stream>>>(hist1, selinfo);
    k_gather<<<dim3(GSPLIT, NBATCH), 256, 0, stream>>>(cls, selinfo, cand, ccnt);
    k_refine<<<NBATCH, 1024, 0, stream>>>(cand, ccnt, selinfo, selk, scnt);
    k_rank_decode<<<dim3(SELCAP / 64, NBATCH), 256, 0, stream>>>(selk, scnt, regs, anchors,
                                                                 img_h, img_w, out_scores,
                                                                 boxes_ws, valid_ws);
    k_supmat<<<dim3(32, 8, NBATCH), 256, 0, stream>>>(boxes_ws, sup);
    k_nms_scan<<<NBATCH, 256, 0, stream>>>(sup, valid_ws, boxes_ws, out_boxes, out_keep);
}